// Round 2
// baseline (6428.484 us; speedup 1.0000x reference)
//
#include <hip/hip_runtime.h>
#include <hip/hip_bf16.h>

#define NN 20000
#define NE 640000
#define DSH 9
#define NB 10
#define M1 64
#define M2 128
#define ATTR 4
#define EPW 16   // edges per wave-iteration (NE % EPW == 0)

constexpr float INV_SQRT_NB = 0.17677669529663687f; // 1/sqrt(32)

__device__ __forceinline__ float silu_f(float x) {
    return x / (1.0f + __expf(-x));
}

// msg-buffer element load/store (f32 or bf16)
__device__ __forceinline__ float msg_ld(const float* p) { return *p; }
__device__ __forceinline__ float msg_ld(const __hip_bfloat16* p) { return __bfloat162float(*p); }
__device__ __forceinline__ void  msg_st(float* p, float v) { *p = v; }
__device__ __forceinline__ void  msg_st(__hip_bfloat16* p, float v) { *p = __float2bfloat16(v); }

__device__ __forceinline__ void load16(float* v, const float* p) {
    const float4* q = (const float4*)p;
    float4 a = q[0], b = q[1], c = q[2], d = q[3];
    v[0]=a.x; v[1]=a.y; v[2]=a.z; v[3]=a.w;
    v[4]=b.x; v[5]=b.y; v[6]=b.z; v[7]=b.w;
    v[8]=c.x; v[9]=c.y; v[10]=c.z; v[11]=c.w;
    v[12]=d.x; v[13]=d.y; v[14]=d.z; v[15]=d.w;
}

// XOR swizzle on float4 index of a [K][16]-f32 tile: v' = (k*4+q) ^ (k&7).
// Bijective; writes (lane-major) spread across all 32 banks; reads are
// lane-broadcast (conflict-free for any bijection).
__device__ __forceinline__ int swz(int k, int q) { return (k * 4 + q) ^ (k & 7); }

__device__ __forceinline__ void load16_swz(float* v, const float4* t4, int k) {
    float4 a = t4[swz(k,0)], b = t4[swz(k,1)], c = t4[swz(k,2)], d = t4[swz(k,3)];
    v[0]=a.x; v[1]=a.y; v[2]=a.z; v[3]=a.w;
    v[4]=b.x; v[5]=b.y; v[6]=b.z; v[7]=b.w;
    v[8]=c.x; v[9]=c.y; v[10]=c.z; v[11]=c.w;
    v[12]=d.x; v[13]=d.y; v[14]=d.z; v[15]=d.w;
}

// ---------------------------------------------------------------------------
// CSR build over dst (once per call, reused by all 3 layers)
// ---------------------------------------------------------------------------
__global__ void count_k(const int* __restrict__ dst, int* __restrict__ cnt) {
    int i = blockIdx.x * blockDim.x + threadIdx.x;
    int st = gridDim.x * blockDim.x;
    for (; i < NE; i += st) atomicAdd(&cnt[dst[i]], 1);
}

__global__ void scan_k(const int* __restrict__ cnt, int* __restrict__ ptr) {
    // single block, 256 threads: strip-sum + Hillis-Steele + strip write-out
    __shared__ int ssum[256];
    const int T = 256, t = threadIdx.x;
    const int strip = (NN + T - 1) / T;
    int base = t * strip, s = 0;
    for (int i = 0; i < strip; i++) { int idx = base + i; if (idx < NN) s += cnt[idx]; }
    ssum[t] = s; __syncthreads();
    for (int off = 1; off < T; off <<= 1) {
        int v = (t >= off) ? ssum[t - off] : 0;
        __syncthreads();
        ssum[t] += v;
        __syncthreads();
    }
    int run = (t == 0) ? 0 : ssum[t - 1];
    for (int i = 0; i < strip; i++) {
        int idx = base + i;
        if (idx < NN) { int c = cnt[idx]; ptr[idx] = run; run += c; }
    }
    if (t == T - 1) ptr[NN] = run;
}

__global__ void fill_k(const int* __restrict__ dst, const int* __restrict__ ptr,
                       int* __restrict__ cnt, int* __restrict__ ids) {
    int i = blockIdx.x * blockDim.x + threadIdx.x;
    int st = gridDim.x * blockDim.x;
    for (; i < NE; i += st) {
        int d = dst[i];
        int r = atomicAdd(&cnt[d], 1);
        ids[ptr[d] + r] = i;
    }
}

// ---------------------------------------------------------------------------
// Per-node prep: xa = x @ A   and   agg = outer(x, attr) @ Wsc  (self-conn)
// ---------------------------------------------------------------------------
template<int DI, int DO, int NT>
__global__ void node_prep(const float* __restrict__ xin,
                          const float* __restrict__ attr,
                          const float* __restrict__ A,
                          const float* __restrict__ Wsc,
                          float* __restrict__ xa,
                          float* __restrict__ agg)
{
    __shared__ float sx[NT][DI];
    __shared__ float sat[NT][ATTR];
    const int n0 = blockIdx.x * NT;
    for (int idx = threadIdx.x; idx < NT * DI; idx += blockDim.x)
        sx[idx / DI][idx % DI] = xin[(size_t)n0 * DI + idx];
    if (threadIdx.x < NT * ATTR)
        sat[threadIdx.x / ATTR][threadIdx.x % ATTR] = attr[(size_t)n0 * ATTR + threadIdx.x];
    __syncthreads();

    const int o = threadIdx.x;
    if (o < DO) {
        float at[NT][ATTR];
        #pragma unroll
        for (int n = 0; n < NT; n++) {
            at[n][0] = sat[n][0]; at[n][1] = sat[n][1];
            at[n][2] = sat[n][2]; at[n][3] = sat[n][3];
        }
        float accA[NT], accS[NT];
        #pragma unroll
        for (int n = 0; n < NT; n++) { accA[n] = 0.f; accS[n] = 0.f; }
        for (int i = 0; i < DI; i++) {
            float a  = A[(size_t)i * DO + o];
            float w0 = Wsc[(size_t)(i * 4 + 0) * DO + o];
            float w1 = Wsc[(size_t)(i * 4 + 1) * DO + o];
            float w2 = Wsc[(size_t)(i * 4 + 2) * DO + o];
            float w3 = Wsc[(size_t)(i * 4 + 3) * DO + o];
            #pragma unroll
            for (int n = 0; n < NT; n++) {
                float xi = sx[n][i];
                accA[n] = fmaf(xi, a, accA[n]);
                float s = fmaf(at[n][3], w3,
                          fmaf(at[n][2], w2,
                          fmaf(at[n][1], w1, at[n][0] * w0)));
                accS[n] = fmaf(xi, s, accS[n]);
            }
        }
        #pragma unroll
        for (int n = 0; n < NT; n++) {
            xa [(size_t)(n0 + n) * DO + o] = accA[n];
            agg[(size_t)(n0 + n) * DO + o] = accS[n];
        }
    }
}

// ---------------------------------------------------------------------------
// Fused edge kernel: radial MLP + tensor-product message.
// MODE 0: store per-edge message to msg[E,DO] (coalesced, no atomics)
// MODE 1: legacy atomic scatter into agg (ws-too-small fallback)
// ---------------------------------------------------------------------------
struct alignas(16) WaveBuf {
    float embT[NB * EPW];   // [10][16]
    float shT [DSH * EPW];  // [9][16]
    float h1T [M1 * EPW];   // [64][16]  (XOR-swizzled float4 layout)
    float h2T [M2 * EPW];   // [128][16] (XOR-swizzled float4 layout)
    int   sidx[EPW];
};

template<int DO, int MODE, typename MsgT>
__global__ void __launch_bounds__(256, 3)
edge_mp(const float* __restrict__ emb,  // [E,10]
        const float* __restrict__ sh,   // [E,9]
        const int*   __restrict__ src,
        const int*   __restrict__ dstg,
        const float* __restrict__ W1g,  // [10][64]
        const float* __restrict__ W2g,  // [64][128]
        const float* __restrict__ W3g,  // [128][DO]
        const float* __restrict__ Bg,   // [9][DO]
        const float* __restrict__ xa,   // [N,DO]
        float* __restrict__ agg,        // [N,DO]   (MODE 1)
        MsgT* __restrict__ msg,         // [E,144]  (MODE 0, DO=144)
        float* __restrict__ msg3)       // [E,3]    (MODE 0, DO=3)
{
    __shared__ WaveBuf wb[4];
    const int wid  = threadIdx.x >> 6;
    const int lane = threadIdx.x & 63;
    WaveBuf& wbuf = wb[wid];
    float4* h14 = (float4*)wbuf.h1T;
    float4* h24 = (float4*)wbuf.h2T;
    const int gwave = blockIdx.x * 4 + wid;
    const int nwave = gridDim.x * 4;
    const int niter = NE / EPW;

    for (int it = gwave; it < niter; it += nwave) {
        const int e0 = it * EPW;
        // ---- stage emb/sh/idx for 16 edges into transposed LDS tiles ----
        {
            const float* ep = emb + (size_t)e0 * NB;
            int f = lane;        wbuf.embT[(f % 10) * EPW + f / 10] = ep[f];
            f = lane + 64;       wbuf.embT[(f % 10) * EPW + f / 10] = ep[f];
            if (lane < 32) { f = lane + 128; wbuf.embT[(f % 10) * EPW + f / 10] = ep[f]; }
            const float* sp = sh + (size_t)e0 * DSH;
            f = lane;            wbuf.shT[(f % 9) * EPW + f / 9] = sp[f];
            f = lane + 64;       wbuf.shT[(f % 9) * EPW + f / 9] = sp[f];
            if (lane < 16) { f = lane + 128; wbuf.shT[(f % 9) * EPW + f / 9] = sp[f]; }
            if (lane < EPW) wbuf.sidx[lane] = src[e0 + lane];
        }
        // ---- phase A: h1 = silu(emb @ W1), lane = hidden unit j ----
        {
            float hacc[EPW];
            #pragma unroll
            for (int e = 0; e < EPW; e++) hacc[e] = 0.f;
            #pragma unroll
            for (int k = 0; k < NB; k++) {
                float w = W1g[k * M1 + lane];
                float ev[EPW]; load16(ev, &wbuf.embT[k * EPW]);
                #pragma unroll
                for (int e = 0; e < EPW; e++) hacc[e] = fmaf(ev[e], w, hacc[e]);
            }
            #pragma unroll
            for (int q = 0; q < 4; q++) {
                float4 o4;
                o4.x = silu_f(hacc[4*q+0]); o4.y = silu_f(hacc[4*q+1]);
                o4.z = silu_f(hacc[4*q+2]); o4.w = silu_f(hacc[4*q+3]);
                h14[swz(lane, q)] = o4;
            }
        }
        // ---- phase B: h2 = silu(h1 @ W2), lane owns j = lane, lane+64 ----
        {
            float b0[EPW], b1[EPW];
            #pragma unroll
            for (int e = 0; e < EPW; e++) { b0[e] = 0.f; b1[e] = 0.f; }
            #pragma unroll 4
            for (int k = 0; k < M1; k++) {
                float w2a = W2g[k * M2 + lane];
                float w2b = W2g[k * M2 + 64 + lane];
                float hv[EPW]; load16_swz(hv, h14, k);
                #pragma unroll
                for (int e = 0; e < EPW; e++) {
                    b0[e] = fmaf(hv[e], w2a, b0[e]);
                    b1[e] = fmaf(hv[e], w2b, b1[e]);
                }
            }
            #pragma unroll
            for (int q = 0; q < 4; q++) {
                float4 o4;
                o4.x = silu_f(b0[4*q+0]); o4.y = silu_f(b0[4*q+1]);
                o4.z = silu_f(b0[4*q+2]); o4.w = silu_f(b0[4*q+3]);
                h24[swz(lane, q)] = o4;
                o4.x = silu_f(b1[4*q+0]); o4.y = silu_f(b1[4*q+1]);
                o4.z = silu_f(b1[4*q+2]); o4.w = silu_f(b1[4*q+3]);
                h24[swz(64 + lane, q)] = o4;
            }
        }

        if constexpr (DO == 3) {
            // ---- small-output path (layer 2): lane -> (edge, o) ----
            const bool act = lane < 48;
            int e = lane / 3;
            int o = lane - 3 * e;
            if (!act) { e = 0; o = 0; }
            const float* h2f = (const float*)wbuf.h2T;
            float gacc = 0.f, sacc = 0.f;
            #pragma unroll 4
            for (int k = 0; k < M2; k++)
                gacc = fmaf(h2f[swz(k, e >> 2) * 4 + (e & 3)], W3g[k * 3 + o], gacc);
            #pragma unroll
            for (int k = 0; k < DSH; k++)
                sacc = fmaf(wbuf.shT[k * EPW + e], Bg[k * 3 + o], sacc);
            if (act) {
                int sN = wbuf.sidx[e];
                float m = gacc * sacc * xa[(size_t)sN * 3 + o] * INV_SQRT_NB;
                if constexpr (MODE == 0) {
                    msg3[(size_t)(e0 + e) * 3 + o] = m;
                } else {
                    int dN = dstg[e0 + e];
                    atomicAdd(&agg[(size_t)dN * 3 + o], m);
                }
            }
        } else {
            // ---- phase C: gate = h2 @ W3, lane owns o = lane, lane+64, lane+128 ----
            const int o3 = 128 + lane;
            float g0[EPW], g1[EPW], g2[EPW];
            #pragma unroll
            for (int e = 0; e < EPW; e++) { g0[e]=0.f; g1[e]=0.f; g2[e]=0.f; }
            #pragma unroll 2
            for (int k = 0; k < M2; k++) {
                float w3a = W3g[(size_t)k * DO + lane];
                float w3b = W3g[(size_t)k * DO + 64 + lane];
                float w3c = (o3 < DO) ? W3g[(size_t)k * DO + o3] : 0.f;
                float hv[EPW]; load16_swz(hv, h24, k);
                #pragma unroll
                for (int e = 0; e < EPW; e++) {
                    g0[e] = fmaf(hv[e], w3a, g0[e]);
                    g1[e] = fmaf(hv[e], w3b, g1[e]);
                    g2[e] = fmaf(hv[e], w3c, g2[e]);
                }
            }
            // ---- phase D: shb = sh @ B ----
            float s0[EPW], s1[EPW], s2[EPW];
            #pragma unroll
            for (int e = 0; e < EPW; e++) { s0[e]=0.f; s1[e]=0.f; s2[e]=0.f; }
            #pragma unroll
            for (int k = 0; k < DSH; k++) {
                float ba = Bg[(size_t)k * DO + lane];
                float bb = Bg[(size_t)k * DO + 64 + lane];
                float bc = (o3 < DO) ? Bg[(size_t)k * DO + o3] : 0.f;
                float sv[EPW]; load16(sv, &wbuf.shT[k * EPW]);
                #pragma unroll
                for (int e = 0; e < EPW; e++) {
                    s0[e] = fmaf(sv[e], ba, s0[e]);
                    s1[e] = fmaf(sv[e], bb, s1[e]);
                    s2[e] = fmaf(sv[e], bc, s2[e]);
                }
            }
            // ---- gather xa[src], combine, emit ----
            #pragma unroll
            for (int e = 0; e < EPW; e++) {
                int sN = wbuf.sidx[e];
                const float* xr = xa + (size_t)sN * DO;
                float m0 = g0[e] * s0[e] * xr[lane]      * INV_SQRT_NB;
                float m1 = g1[e] * s1[e] * xr[64 + lane] * INV_SQRT_NB;
                float m2 = (o3 < DO) ? g2[e] * s2[e] * xr[o3] * INV_SQRT_NB : 0.f;
                if constexpr (MODE == 0) {
                    MsgT* mr = msg + (size_t)(e0 + e) * DO;
                    msg_st(&mr[lane], m0);
                    msg_st(&mr[64 + lane], m1);
                    if (o3 < DO) msg_st(&mr[o3], m2);
                } else {
                    int dN = dstg[e0 + e];
                    float* ar = agg + (size_t)dN * DO;
                    atomicAdd(&ar[lane], m0);
                    atomicAdd(&ar[64 + lane], m1);
                    if (o3 < DO) atomicAdd(&ar[o3], m2);
                }
            }
        }
    }
}

// ---------------------------------------------------------------------------
// CSR gather: wave per node, sums msg rows in registers, + self-conn, silu
// ---------------------------------------------------------------------------
template<typename MsgT, int ACT>
__global__ void gather144(const MsgT* __restrict__ msg,
                          const int*  __restrict__ ids,
                          const int*  __restrict__ ptr,
                          const float* __restrict__ sc,
                          float* __restrict__ outb)
{
    const int lane = threadIdx.x & 63;
    const int gw = blockIdx.x * (blockDim.x >> 6) + (threadIdx.x >> 6);
    const int nw = gridDim.x * (blockDim.x >> 6);
    for (int n = gw; n < NN; n += nw) {
        const int s0 = ptr[n], s1 = ptr[n + 1];
        float a0 = 0.f, a1 = 0.f, a2 = 0.f;
        int s = s0;
        int eNext = (s < s1) ? ids[s] : 0;
        while (s < s1) {
            int e = eNext;
            eNext = (s + 1 < s1) ? ids[s + 1] : 0;
            s++;
            const MsgT* r = msg + (size_t)e * 144;
            a0 += msg_ld(&r[lane]);
            a1 += msg_ld(&r[64 + lane]);
            if (lane < 16) a2 += msg_ld(&r[128 + lane]);
        }
        float v0 = sc[(size_t)n * 144 + lane] + a0;
        float v1 = sc[(size_t)n * 144 + 64 + lane] + a1;
        if (ACT) { v0 = silu_f(v0); v1 = silu_f(v1); }
        outb[(size_t)n * 144 + lane] = v0;
        outb[(size_t)n * 144 + 64 + lane] = v1;
        if (lane < 16) {
            float v2 = sc[(size_t)n * 144 + 128 + lane] + a2;
            if (ACT) v2 = silu_f(v2);
            outb[(size_t)n * 144 + 128 + lane] = v2;
        }
    }
}

__global__ void gather3(const float* __restrict__ msg3,
                        const int*  __restrict__ ids,
                        const int*  __restrict__ ptr,
                        float* __restrict__ outb)
{
    int t = blockIdx.x * blockDim.x + threadIdx.x;
    if (t >= NN * 3) return;
    int n = t / 3, o = t - 3 * n;
    float a = 0.f;
    for (int s = ptr[n]; s < ptr[n + 1]; s++) {
        int e = ids[s];
        a += msg3[(size_t)e * 3 + o];
    }
    outb[t] += a;   // self-connection already written by node_prep
}

__global__ void silu_kernel(const float* __restrict__ in, float* __restrict__ out, int n)
{
    int i = blockIdx.x * blockDim.x + threadIdx.x;
    int st = gridDim.x * blockDim.x;
    for (; i < n; i += st) out[i] = silu_f(in[i]);
}

// ---------------------------------------------------------------------------
extern "C" void kernel_launch(void* const* d_in, const int* in_sizes, int n_in,
                              void* d_out, int out_size, void* d_ws, size_t ws_size,
                              hipStream_t stream) {
    const float* x    = (const float*)d_in[0];
    const float* attr = (const float*)d_in[1];
    const float* sh   = (const float*)d_in[2];
    const float* emb  = (const float*)d_in[3];
    const float* A0   = (const float*)d_in[4];
    const float* B0   = (const float*)d_in[5];
    const float* W1_0 = (const float*)d_in[6];
    const float* W2_0 = (const float*)d_in[7];
    const float* W3_0 = (const float*)d_in[8];
    const float* Wsc0 = (const float*)d_in[9];
    const float* A1   = (const float*)d_in[10];
    const float* B1   = (const float*)d_in[11];
    const float* W1_1 = (const float*)d_in[12];
    const float* W2_1 = (const float*)d_in[13];
    const float* W3_1 = (const float*)d_in[14];
    const float* Wsc1 = (const float*)d_in[15];
    const float* A2   = (const float*)d_in[16];
    const float* B2   = (const float*)d_in[17];
    const float* W1_2 = (const float*)d_in[18];
    const float* W2_2 = (const float*)d_in[19];
    const float* W3_2 = (const float*)d_in[20];
    const float* Wsc2 = (const float*)d_in[21];
    const int*   src  = (const int*)d_in[22];
    const int*   dst  = (const int*)d_in[23];
    float* out = (float*)d_out;

    // ---- carve workspace ----
    char* wp = (char*)d_ws;
    auto alloc = [&](size_t bytes) -> void* {
        void* r = (void*)wp;
        wp += (bytes + 255) & ~(size_t)255;
        return r;
    };
    float* xa  = (float*)alloc((size_t)NN * 144 * 4);
    float* agg = (float*)alloc((size_t)NN * 144 * 4);
    float* hb0 = (float*)alloc((size_t)NN * 144 * 4);
    float* hb1 = (float*)alloc((size_t)NN * 144 * 4);
    int*   cnt = (int*)alloc((size_t)NN * 4);
    int*   ptr = (int*)alloc((size_t)(NN + 1) * 4);
    int*   ids = (int*)alloc((size_t)NE * 4);
    size_t base_used = (size_t)(wp - (char*)d_ws);
    size_t need_f32  = base_used + (size_t)NE * 144 * 4;
    size_t need_bf16 = base_used + (size_t)NE * 144 * 2;
    void* msgbuf = (void*)wp;
    float* msg3 = (float*)msgbuf;   // layer-2 messages alias the msg buffer

    const int mode = (ws_size >= need_f32) ? 0 : (ws_size >= need_bf16 ? 1 : 2);

    if (mode == 2) {
        // legacy atomic fallback (tiny ws)
        node_prep<64, 144, 8><<<NN / 8, 192, 0, stream>>>(x, attr, A0, Wsc0, xa, agg);
        edge_mp<144, 1, float><<<768, 256, 0, stream>>>(emb, sh, src, dst, W1_0, W2_0, W3_0, B0, xa, agg, nullptr, nullptr);
        silu_kernel<<<2048, 256, 0, stream>>>(agg, hb0, NN * 144);
        node_prep<144, 144, 8><<<NN / 8, 192, 0, stream>>>(hb0, attr, A1, Wsc1, xa, agg);
        edge_mp<144, 1, float><<<768, 256, 0, stream>>>(emb, sh, src, dst, W1_1, W2_1, W3_1, B1, xa, agg, nullptr, nullptr);
        silu_kernel<<<2048, 256, 0, stream>>>(agg, hb1, NN * 144);
        node_prep<144, 3, 8><<<NN / 8, 192, 0, stream>>>(hb1, attr, A2, Wsc2, xa, out);
        edge_mp<3, 1, float><<<768, 256, 0, stream>>>(emb, sh, src, dst, W1_2, W2_2, W3_2, B2, xa, out, nullptr, nullptr);
        return;
    }

    // ---- CSR build (once; dst identical for all layers) ----
    hipMemsetAsync(cnt, 0, (size_t)NN * 4, stream);
    count_k<<<1024, 256, 0, stream>>>(dst, cnt);
    scan_k<<<1, 256, 0, stream>>>(cnt, ptr);
    hipMemsetAsync(cnt, 0, (size_t)NN * 4, stream);
    fill_k<<<1024, 256, 0, stream>>>(dst, ptr, cnt, ids);

    if (mode == 0) {
        float* msg = (float*)msgbuf;
        node_prep<64, 144, 8><<<NN / 8, 192, 0, stream>>>(x, attr, A0, Wsc0, xa, agg);
        edge_mp<144, 0, float><<<768, 256, 0, stream>>>(emb, sh, src, dst, W1_0, W2_0, W3_0, B0, xa, agg, msg, msg3);
        gather144<float, 1><<<5000, 256, 0, stream>>>(msg, ids, ptr, agg, hb0);

        node_prep<144, 144, 8><<<NN / 8, 192, 0, stream>>>(hb0, attr, A1, Wsc1, xa, agg);
        edge_mp<144, 0, float><<<768, 256, 0, stream>>>(emb, sh, src, dst, W1_1, W2_1, W3_1, B1, xa, agg, msg, msg3);
        gather144<float, 1><<<5000, 256, 0, stream>>>(msg, ids, ptr, agg, hb1);

        node_prep<144, 3, 8><<<NN / 8, 192, 0, stream>>>(hb1, attr, A2, Wsc2, xa, out);
        edge_mp<3, 0, float><<<768, 256, 0, stream>>>(emb, sh, src, dst, W1_2, W2_2, W3_2, B2, xa, out, msg, msg3);
        gather3<<<(NN * 3 + 255) / 256, 256, 0, stream>>>(msg3, ids, ptr, out);
    } else {
        __hip_bfloat16* msg = (__hip_bfloat16*)msgbuf;
        node_prep<64, 144, 8><<<NN / 8, 192, 0, stream>>>(x, attr, A0, Wsc0, xa, agg);
        edge_mp<144, 0, __hip_bfloat16><<<768, 256, 0, stream>>>(emb, sh, src, dst, W1_0, W2_0, W3_0, B0, xa, agg, msg, msg3);
        gather144<__hip_bfloat16, 1><<<5000, 256, 0, stream>>>(msg, ids, ptr, agg, hb0);

        node_prep<144, 144, 8><<<NN / 8, 192, 0, stream>>>(hb0, attr, A1, Wsc1, xa, agg);
        edge_mp<144, 0, __hip_bfloat16><<<768, 256, 0, stream>>>(emb, sh, src, dst, W1_1, W2_1, W3_1, B1, xa, agg, msg, msg3);
        gather144<__hip_bfloat16, 1><<<5000, 256, 0, stream>>>(msg, ids, ptr, agg, hb1);

        node_prep<144, 3, 8><<<NN / 8, 192, 0, stream>>>(hb1, attr, A2, Wsc2, xa, out);
        edge_mp<3, 0, __hip_bfloat16><<<768, 256, 0, stream>>>(emb, sh, src, dst, W1_2, W2_2, W3_2, B2, xa, out, msg, msg3);
        gather3<<<(NN * 3 + 255) / 256, 256, 0, stream>>>(msg3, ids, ptr, out);
    }
}

// Round 3
// 3151.690 us; speedup vs baseline: 2.0397x; 2.0397x over previous
//
#include <hip/hip_runtime.h>
#include <hip/hip_bf16.h>

#define NN 20000
#define NE 640000
#define DSH 9
#define NB 10
#define M1 64
#define M2 128
#define ATTR 4
#define EPW 16   // edges per wave-iteration (NE % EPW == 0)

constexpr float INV_SQRT_NB = 0.17677669529663687f; // 1/sqrt(32)

__device__ __forceinline__ float silu_f(float x) {
    return x / (1.0f + __expf(-x));
}

// msg-buffer element load/store (f32 or bf16)
__device__ __forceinline__ float msg_ld(const float* p) { return *p; }
__device__ __forceinline__ float msg_ld(const __hip_bfloat16* p) { return __bfloat162float(*p); }
__device__ __forceinline__ void  msg_st(float* p, float v) { *p = v; }
__device__ __forceinline__ void  msg_st(__hip_bfloat16* p, float v) { *p = __float2bfloat16(v); }

__device__ __forceinline__ void load16(float* v, const float* p) {
    const float4* q = (const float4*)p;
    float4 a = q[0], b = q[1], c = q[2], d = q[3];
    v[0]=a.x; v[1]=a.y; v[2]=a.z; v[3]=a.w;
    v[4]=b.x; v[5]=b.y; v[6]=b.z; v[7]=b.w;
    v[8]=c.x; v[9]=c.y; v[10]=c.z; v[11]=c.w;
    v[12]=d.x; v[13]=d.y; v[14]=d.z; v[15]=d.w;
}

// XOR swizzle on float4 index of a [K][16]-f32 tile: v' = (k*4+q) ^ (k&7).
// Bijective; writes (lane-major) spread across banks; reads are lane-broadcast.
// R2 evidence: SQ_LDS_BANK_CONFLICT 1.8e7 -> 1.6e6.
__device__ __forceinline__ int swz(int k, int q) { return (k * 4 + q) ^ (k & 7); }

__device__ __forceinline__ void load16_swz(float* v, const float4* t4, int k) {
    float4 a = t4[swz(k,0)], b = t4[swz(k,1)], c = t4[swz(k,2)], d = t4[swz(k,3)];
    v[0]=a.x; v[1]=a.y; v[2]=a.z; v[3]=a.w;
    v[4]=b.x; v[5]=b.y; v[6]=b.z; v[7]=b.w;
    v[8]=c.x; v[9]=c.y; v[10]=c.z; v[11]=c.w;
    v[12]=d.x; v[13]=d.y; v[14]=d.z; v[15]=d.w;
}

// ---------------------------------------------------------------------------
// CSR build over dst (once per call, reused by all 3 layers)
// ---------------------------------------------------------------------------
__global__ void count_k(const int* __restrict__ dst, int* __restrict__ cnt) {
    int i = blockIdx.x * blockDim.x + threadIdx.x;
    int st = gridDim.x * blockDim.x;
    for (; i < NE; i += st) atomicAdd(&cnt[dst[i]], 1);
}

__global__ void scan_k(const int* __restrict__ cnt, int* __restrict__ ptr) {
    __shared__ int ssum[256];
    const int T = 256, t = threadIdx.x;
    const int strip = (NN + T - 1) / T;
    int base = t * strip, s = 0;
    for (int i = 0; i < strip; i++) { int idx = base + i; if (idx < NN) s += cnt[idx]; }
    ssum[t] = s; __syncthreads();
    for (int off = 1; off < T; off <<= 1) {
        int v = (t >= off) ? ssum[t - off] : 0;
        __syncthreads();
        ssum[t] += v;
        __syncthreads();
    }
    int run = (t == 0) ? 0 : ssum[t - 1];
    for (int i = 0; i < strip; i++) {
        int idx = base + i;
        if (idx < NN) { int c = cnt[idx]; ptr[idx] = run; run += c; }
    }
    if (t == T - 1) ptr[NN] = run;
}

__global__ void fill_k(const int* __restrict__ dst, const int* __restrict__ ptr,
                       int* __restrict__ cnt, int* __restrict__ ids) {
    int i = blockIdx.x * blockDim.x + threadIdx.x;
    int st = gridDim.x * blockDim.x;
    for (; i < NE; i += st) {
        int d = dst[i];
        int r = atomicAdd(&cnt[d], 1);
        ids[ptr[d] + r] = i;
    }
}

// ---------------------------------------------------------------------------
// Per-node prep: xa = x @ A   and   agg = outer(x, attr) @ Wsc  (self-conn)
// ---------------------------------------------------------------------------
template<int DI, int DO, int NT>
__global__ void node_prep(const float* __restrict__ xin,
                          const float* __restrict__ attr,
                          const float* __restrict__ A,
                          const float* __restrict__ Wsc,
                          float* __restrict__ xa,
                          float* __restrict__ agg)
{
    __shared__ float sx[NT][DI];
    __shared__ float sat[NT][ATTR];
    const int n0 = blockIdx.x * NT;
    for (int idx = threadIdx.x; idx < NT * DI; idx += blockDim.x)
        sx[idx / DI][idx % DI] = xin[(size_t)n0 * DI + idx];
    if (threadIdx.x < NT * ATTR)
        sat[threadIdx.x / ATTR][threadIdx.x % ATTR] = attr[(size_t)n0 * ATTR + threadIdx.x];
    __syncthreads();

    const int o = threadIdx.x;
    if (o < DO) {
        float at[NT][ATTR];
        #pragma unroll
        for (int n = 0; n < NT; n++) {
            at[n][0] = sat[n][0]; at[n][1] = sat[n][1];
            at[n][2] = sat[n][2]; at[n][3] = sat[n][3];
        }
        float accA[NT], accS[NT];
        #pragma unroll
        for (int n = 0; n < NT; n++) { accA[n] = 0.f; accS[n] = 0.f; }
        for (int i = 0; i < DI; i++) {
            float a  = A[(size_t)i * DO + o];
            float w0 = Wsc[(size_t)(i * 4 + 0) * DO + o];
            float w1 = Wsc[(size_t)(i * 4 + 1) * DO + o];
            float w2 = Wsc[(size_t)(i * 4 + 2) * DO + o];
            float w3 = Wsc[(size_t)(i * 4 + 3) * DO + o];
            #pragma unroll
            for (int n = 0; n < NT; n++) {
                float xi = sx[n][i];
                accA[n] = fmaf(xi, a, accA[n]);
                float s = fmaf(at[n][3], w3,
                          fmaf(at[n][2], w2,
                          fmaf(at[n][1], w1, at[n][0] * w0)));
                accS[n] = fmaf(xi, s, accS[n]);
            }
        }
        #pragma unroll
        for (int n = 0; n < NT; n++) {
            xa [(size_t)(n0 + n) * DO + o] = accA[n];
            agg[(size_t)(n0 + n) * DO + o] = accS[n];
        }
    }
}

// ---------------------------------------------------------------------------
// Fused edge kernel: radial MLP + tensor-product message.
// MODE 0: store per-edge message to msg[E,DO] (coalesced, no atomics)
// MODE 1: legacy atomic scatter into agg (ws-too-small fallback)
// NOTE: __launch_bounds__(256,2) — (256,3) capped VGPRs at 84 and spilled
// ~620 MB/dispatch of scratch traffic (R2 post-mortem). 128 VGPR is the
// known-good config (R1: zero spill evidence).
// ---------------------------------------------------------------------------
struct alignas(16) WaveBuf {
    float embT[NB * EPW];   // [10][16]
    float shT [DSH * EPW];  // [9][16]
    float h1T [M1 * EPW];   // [64][16]  (XOR-swizzled float4 layout)
    float h2T [M2 * EPW];   // [128][16] (XOR-swizzled float4 layout)
    int   sidx[EPW];
};

template<int DO, int MODE, typename MsgT>
__global__ void __launch_bounds__(256, 2)
edge_mp(const float* __restrict__ emb,  // [E,10]
        const float* __restrict__ sh,   // [E,9]
        const int*   __restrict__ src,
        const int*   __restrict__ dstg,
        const float* __restrict__ W1g,  // [10][64]
        const float* __restrict__ W2g,  // [64][128]
        const float* __restrict__ W3g,  // [128][DO]
        const float* __restrict__ Bg,   // [9][DO]
        const float* __restrict__ xa,   // [N,DO]
        float* __restrict__ agg,        // [N,DO]   (MODE 1)
        MsgT* __restrict__ msg,         // [E,144]  (MODE 0, DO=144)
        float* __restrict__ msg3)       // [E,3]    (MODE 0, DO=3)
{
    __shared__ WaveBuf wb[4];
    const int wid  = threadIdx.x >> 6;
    const int lane = threadIdx.x & 63;
    WaveBuf& wbuf = wb[wid];
    float4* h14 = (float4*)wbuf.h1T;
    float4* h24 = (float4*)wbuf.h2T;
    const int gwave = blockIdx.x * 4 + wid;
    const int nwave = gridDim.x * 4;
    const int niter = NE / EPW;

    for (int it = gwave; it < niter; it += nwave) {
        const int e0 = it * EPW;
        // ---- stage emb/sh/idx for 16 edges into transposed LDS tiles ----
        {
            const float* ep = emb + (size_t)e0 * NB;
            int f = lane;        wbuf.embT[(f % 10) * EPW + f / 10] = ep[f];
            f = lane + 64;       wbuf.embT[(f % 10) * EPW + f / 10] = ep[f];
            if (lane < 32) { f = lane + 128; wbuf.embT[(f % 10) * EPW + f / 10] = ep[f]; }
            const float* sp = sh + (size_t)e0 * DSH;
            f = lane;            wbuf.shT[(f % 9) * EPW + f / 9] = sp[f];
            f = lane + 64;       wbuf.shT[(f % 9) * EPW + f / 9] = sp[f];
            if (lane < 16) { f = lane + 128; wbuf.shT[(f % 9) * EPW + f / 9] = sp[f]; }
            if (lane < EPW) wbuf.sidx[lane] = src[e0 + lane];
        }
        // ---- phase A: h1 = silu(emb @ W1), lane = hidden unit j ----
        {
            float hacc[EPW];
            #pragma unroll
            for (int e = 0; e < EPW; e++) hacc[e] = 0.f;
            #pragma unroll
            for (int k = 0; k < NB; k++) {
                float w = W1g[k * M1 + lane];
                float ev[EPW]; load16(ev, &wbuf.embT[k * EPW]);
                #pragma unroll
                for (int e = 0; e < EPW; e++) hacc[e] = fmaf(ev[e], w, hacc[e]);
            }
            #pragma unroll
            for (int q = 0; q < 4; q++) {
                float4 o4;
                o4.x = silu_f(hacc[4*q+0]); o4.y = silu_f(hacc[4*q+1]);
                o4.z = silu_f(hacc[4*q+2]); o4.w = silu_f(hacc[4*q+3]);
                h14[swz(lane, q)] = o4;
            }
        }
        // ---- phase B: h2 = silu(h1 @ W2), lane owns j = lane, lane+64 ----
        {
            float b0[EPW], b1[EPW];
            #pragma unroll
            for (int e = 0; e < EPW; e++) { b0[e] = 0.f; b1[e] = 0.f; }
            #pragma unroll 4
            for (int k = 0; k < M1; k++) {
                float w2a = W2g[k * M2 + lane];
                float w2b = W2g[k * M2 + 64 + lane];
                float hv[EPW]; load16_swz(hv, h14, k);
                #pragma unroll
                for (int e = 0; e < EPW; e++) {
                    b0[e] = fmaf(hv[e], w2a, b0[e]);
                    b1[e] = fmaf(hv[e], w2b, b1[e]);
                }
            }
            #pragma unroll
            for (int q = 0; q < 4; q++) {
                float4 o4;
                o4.x = silu_f(b0[4*q+0]); o4.y = silu_f(b0[4*q+1]);
                o4.z = silu_f(b0[4*q+2]); o4.w = silu_f(b0[4*q+3]);
                h24[swz(lane, q)] = o4;
                o4.x = silu_f(b1[4*q+0]); o4.y = silu_f(b1[4*q+1]);
                o4.z = silu_f(b1[4*q+2]); o4.w = silu_f(b1[4*q+3]);
                h24[swz(64 + lane, q)] = o4;
            }
        }

        if constexpr (DO == 3) {
            // ---- small-output path (layer 2): lane -> (edge, o) ----
            const bool act = lane < 48;
            int e = lane / 3;
            int o = lane - 3 * e;
            if (!act) { e = 0; o = 0; }
            const float* h2f = (const float*)wbuf.h2T;
            float gacc = 0.f, sacc = 0.f;
            #pragma unroll 4
            for (int k = 0; k < M2; k++)
                gacc = fmaf(h2f[swz(k, e >> 2) * 4 + (e & 3)], W3g[k * 3 + o], gacc);
            #pragma unroll
            for (int k = 0; k < DSH; k++)
                sacc = fmaf(wbuf.shT[k * EPW + e], Bg[k * 3 + o], sacc);
            if (act) {
                int sN = wbuf.sidx[e];
                float m = gacc * sacc * xa[(size_t)sN * 3 + o] * INV_SQRT_NB;
                if constexpr (MODE == 0) {
                    msg3[(size_t)(e0 + e) * 3 + o] = m;
                } else {
                    int dN = dstg[e0 + e];
                    atomicAdd(&agg[(size_t)dN * 3 + o], m);
                }
            }
        } else {
            // ---- phase C: gate = h2 @ W3, lane owns o = lane, lane+64, lane+128 ----
            const int o3 = 128 + lane;
            float g0[EPW], g1[EPW], g2[EPW];
            #pragma unroll
            for (int e = 0; e < EPW; e++) { g0[e]=0.f; g1[e]=0.f; g2[e]=0.f; }
            #pragma unroll 2
            for (int k = 0; k < M2; k++) {
                float w3a = W3g[(size_t)k * DO + lane];
                float w3b = W3g[(size_t)k * DO + 64 + lane];
                float w3c = (o3 < DO) ? W3g[(size_t)k * DO + o3] : 0.f;
                float hv[EPW]; load16_swz(hv, h24, k);
                #pragma unroll
                for (int e = 0; e < EPW; e++) {
                    g0[e] = fmaf(hv[e], w3a, g0[e]);
                    g1[e] = fmaf(hv[e], w3b, g1[e]);
                    g2[e] = fmaf(hv[e], w3c, g2[e]);
                }
            }
            // ---- phase D: shb = sh @ B ----
            float s0[EPW], s1[EPW], s2[EPW];
            #pragma unroll
            for (int e = 0; e < EPW; e++) { s0[e]=0.f; s1[e]=0.f; s2[e]=0.f; }
            #pragma unroll
            for (int k = 0; k < DSH; k++) {
                float ba = Bg[(size_t)k * DO + lane];
                float bb = Bg[(size_t)k * DO + 64 + lane];
                float bc = (o3 < DO) ? Bg[(size_t)k * DO + o3] : 0.f;
                float sv[EPW]; load16(sv, &wbuf.shT[k * EPW]);
                #pragma unroll
                for (int e = 0; e < EPW; e++) {
                    s0[e] = fmaf(sv[e], ba, s0[e]);
                    s1[e] = fmaf(sv[e], bb, s1[e]);
                    s2[e] = fmaf(sv[e], bc, s2[e]);
                }
            }
            // ---- gather xa[src], combine, emit ----
            #pragma unroll
            for (int e = 0; e < EPW; e++) {
                int sN = wbuf.sidx[e];
                const float* xr = xa + (size_t)sN * DO;
                float m0 = g0[e] * s0[e] * xr[lane]      * INV_SQRT_NB;
                float m1 = g1[e] * s1[e] * xr[64 + lane] * INV_SQRT_NB;
                float m2 = (o3 < DO) ? g2[e] * s2[e] * xr[o3] * INV_SQRT_NB : 0.f;
                if constexpr (MODE == 0) {
                    MsgT* mr = msg + (size_t)(e0 + e) * DO;
                    msg_st(&mr[lane], m0);
                    msg_st(&mr[64 + lane], m1);
                    if (o3 < DO) msg_st(&mr[o3], m2);
                } else {
                    int dN = dstg[e0 + e];
                    float* ar = agg + (size_t)dN * DO;
                    atomicAdd(&ar[lane], m0);
                    atomicAdd(&ar[64 + lane], m1);
                    if (o3 < DO) atomicAdd(&ar[o3], m2);
                }
            }
        }
    }
}

// ---------------------------------------------------------------------------
// CSR gather: wave per node, sums msg rows in registers, + self-conn, silu
// ---------------------------------------------------------------------------
template<typename MsgT, int ACT>
__global__ void gather144(const MsgT* __restrict__ msg,
                          const int*  __restrict__ ids,
                          const int*  __restrict__ ptr,
                          const float* __restrict__ sc,
                          float* __restrict__ outb)
{
    const int lane = threadIdx.x & 63;
    const int gw = blockIdx.x * (blockDim.x >> 6) + (threadIdx.x >> 6);
    const int nw = gridDim.x * (blockDim.x >> 6);
    for (int n = gw; n < NN; n += nw) {
        const int s0 = ptr[n], s1 = ptr[n + 1];
        float a0 = 0.f, a1 = 0.f, a2 = 0.f;
        int s = s0;
        int eNext = (s < s1) ? ids[s] : 0;
        while (s < s1) {
            int e = eNext;
            eNext = (s + 1 < s1) ? ids[s + 1] : 0;
            s++;
            const MsgT* r = msg + (size_t)e * 144;
            a0 += msg_ld(&r[lane]);
            a1 += msg_ld(&r[64 + lane]);
            if (lane < 16) a2 += msg_ld(&r[128 + lane]);
        }
        float v0 = sc[(size_t)n * 144 + lane] + a0;
        float v1 = sc[(size_t)n * 144 + 64 + lane] + a1;
        if (ACT) { v0 = silu_f(v0); v1 = silu_f(v1); }
        outb[(size_t)n * 144 + lane] = v0;
        outb[(size_t)n * 144 + 64 + lane] = v1;
        if (lane < 16) {
            float v2 = sc[(size_t)n * 144 + 128 + lane] + a2;
            if (ACT) v2 = silu_f(v2);
            outb[(size_t)n * 144 + 128 + lane] = v2;
        }
    }
}

__global__ void gather3(const float* __restrict__ msg3,
                        const int*  __restrict__ ids,
                        const int*  __restrict__ ptr,
                        float* __restrict__ outb)
{
    int t = blockIdx.x * blockDim.x + threadIdx.x;
    if (t >= NN * 3) return;
    int n = t / 3, o = t - 3 * n;
    float a = 0.f;
    for (int s = ptr[n]; s < ptr[n + 1]; s++) {
        int e = ids[s];
        a += msg3[(size_t)e * 3 + o];
    }
    outb[t] += a;   // self-connection already written by node_prep
}

__global__ void silu_kernel(const float* __restrict__ in, float* __restrict__ out, int n)
{
    int i = blockIdx.x * blockDim.x + threadIdx.x;
    int st = gridDim.x * blockDim.x;
    for (; i < n; i += st) out[i] = silu_f(in[i]);
}

// ---------------------------------------------------------------------------
extern "C" void kernel_launch(void* const* d_in, const int* in_sizes, int n_in,
                              void* d_out, int out_size, void* d_ws, size_t ws_size,
                              hipStream_t stream) {
    const float* x    = (const float*)d_in[0];
    const float* attr = (const float*)d_in[1];
    const float* sh   = (const float*)d_in[2];
    const float* emb  = (const float*)d_in[3];
    const float* A0   = (const float*)d_in[4];
    const float* B0   = (const float*)d_in[5];
    const float* W1_0 = (const float*)d_in[6];
    const float* W2_0 = (const float*)d_in[7];
    const float* W3_0 = (const float*)d_in[8];
    const float* Wsc0 = (const float*)d_in[9];
    const float* A1   = (const float*)d_in[10];
    const float* B1   = (const float*)d_in[11];
    const float* W1_1 = (const float*)d_in[12];
    const float* W2_1 = (const float*)d_in[13];
    const float* W3_1 = (const float*)d_in[14];
    const float* Wsc1 = (const float*)d_in[15];
    const float* A2   = (const float*)d_in[16];
    const float* B2   = (const float*)d_in[17];
    const float* W1_2 = (const float*)d_in[18];
    const float* W2_2 = (const float*)d_in[19];
    const float* W3_2 = (const float*)d_in[20];
    const float* Wsc2 = (const float*)d_in[21];
    const int*   src  = (const int*)d_in[22];
    const int*   dst  = (const int*)d_in[23];
    float* out = (float*)d_out;

    // ---- carve workspace ----
    char* wp = (char*)d_ws;
    auto alloc = [&](size_t bytes) -> void* {
        void* r = (void*)wp;
        wp += (bytes + 255) & ~(size_t)255;
        return r;
    };
    float* xa  = (float*)alloc((size_t)NN * 144 * 4);
    float* agg = (float*)alloc((size_t)NN * 144 * 4);
    float* hb0 = (float*)alloc((size_t)NN * 144 * 4);
    float* hb1 = (float*)alloc((size_t)NN * 144 * 4);
    int*   cnt = (int*)alloc((size_t)NN * 4);
    int*   ptr = (int*)alloc((size_t)(NN + 1) * 4);
    int*   ids = (int*)alloc((size_t)NE * 4);
    size_t base_used = (size_t)(wp - (char*)d_ws);
    size_t need_f32  = base_used + (size_t)NE * 144 * 4;
    size_t need_bf16 = base_used + (size_t)NE * 144 * 2;
    void* msgbuf = (void*)wp;
    float* msg3 = (float*)msgbuf;   // layer-2 messages alias the msg buffer

    const int mode = (ws_size >= need_f32) ? 0 : (ws_size >= need_bf16 ? 1 : 2);

    if (mode == 2) {
        // legacy atomic fallback (tiny ws)
        node_prep<64, 144, 8><<<NN / 8, 192, 0, stream>>>(x, attr, A0, Wsc0, xa, agg);
        edge_mp<144, 1, float><<<512, 256, 0, stream>>>(emb, sh, src, dst, W1_0, W2_0, W3_0, B0, xa, agg, nullptr, nullptr);
        silu_kernel<<<2048, 256, 0, stream>>>(agg, hb0, NN * 144);
        node_prep<144, 144, 8><<<NN / 8, 192, 0, stream>>>(hb0, attr, A1, Wsc1, xa, agg);
        edge_mp<144, 1, float><<<512, 256, 0, stream>>>(emb, sh, src, dst, W1_1, W2_1, W3_1, B1, xa, agg, nullptr, nullptr);
        silu_kernel<<<2048, 256, 0, stream>>>(agg, hb1, NN * 144);
        node_prep<144, 3, 8><<<NN / 8, 192, 0, stream>>>(hb1, attr, A2, Wsc2, xa, out);
        edge_mp<3, 1, float><<<512, 256, 0, stream>>>(emb, sh, src, dst, W1_2, W2_2, W3_2, B2, xa, out, nullptr, nullptr);
        return;
    }

    // ---- CSR build (once; dst identical for all layers) ----
    hipMemsetAsync(cnt, 0, (size_t)NN * 4, stream);
    count_k<<<1024, 256, 0, stream>>>(dst, cnt);
    scan_k<<<1, 256, 0, stream>>>(cnt, ptr);
    hipMemsetAsync(cnt, 0, (size_t)NN * 4, stream);
    fill_k<<<1024, 256, 0, stream>>>(dst, ptr, cnt, ids);

    if (mode == 0) {
        float* msg = (float*)msgbuf;
        node_prep<64, 144, 8><<<NN / 8, 192, 0, stream>>>(x, attr, A0, Wsc0, xa, agg);
        edge_mp<144, 0, float><<<512, 256, 0, stream>>>(emb, sh, src, dst, W1_0, W2_0, W3_0, B0, xa, agg, msg, msg3);
        gather144<float, 1><<<5000, 256, 0, stream>>>(msg, ids, ptr, agg, hb0);

        node_prep<144, 144, 8><<<NN / 8, 192, 0, stream>>>(hb0, attr, A1, Wsc1, xa, agg);
        edge_mp<144, 0, float><<<512, 256, 0, stream>>>(emb, sh, src, dst, W1_1, W2_1, W3_1, B1, xa, agg, msg, msg3);
        gather144<float, 1><<<5000, 256, 0, stream>>>(msg, ids, ptr, agg, hb1);

        node_prep<144, 3, 8><<<NN / 8, 192, 0, stream>>>(hb1, attr, A2, Wsc2, xa, out);
        edge_mp<3, 0, float><<<512, 256, 0, stream>>>(emb, sh, src, dst, W1_2, W2_2, W3_2, B2, xa, out, msg, msg3);
        gather3<<<(NN * 3 + 255) / 256, 256, 0, stream>>>(msg3, ids, ptr, out);
    } else {
        __hip_bfloat16* msg = (__hip_bfloat16*)msgbuf;
        node_prep<64, 144, 8><<<NN / 8, 192, 0, stream>>>(x, attr, A0, Wsc0, xa, agg);
        edge_mp<144, 0, __hip_bfloat16><<<512, 256, 0, stream>>>(emb, sh, src, dst, W1_0, W2_0, W3_0, B0, xa, agg, msg, msg3);
        gather144<__hip_bfloat16, 1><<<5000, 256, 0, stream>>>(msg, ids, ptr, agg, hb0);

        node_prep<144, 144, 8><<<NN / 8, 192, 0, stream>>>(hb0, attr, A1, Wsc1, xa, agg);
        edge_mp<144, 0, __hip_bfloat16><<<512, 256, 0, stream>>>(emb, sh, src, dst, W1_1, W2_1, W3_1, B1, xa, agg, msg, msg3);
        gather144<__hip_bfloat16, 1><<<5000, 256, 0, stream>>>(msg, ids, ptr, agg, hb1);

        node_prep<144, 3, 8><<<NN / 8, 192, 0, stream>>>(hb1, attr, A2, Wsc2, xa, out);
        edge_mp<3, 0, __hip_bfloat16><<<512, 256, 0, stream>>>(emb, sh, src, dst, W1_2, W2_2, W3_2, B2, xa, out, msg, msg3);
        gather3<<<(NN * 3 + 255) / 256, 256, 0, stream>>>(msg3, ids, ptr, out);
    }
}

// Round 4
// 1541.898 us; speedup vs baseline: 4.1692x; 2.0440x over previous
//
#include <hip/hip_runtime.h>
#include <hip/hip_bf16.h>

#define NN 20000
#define NE 640000
#define DSH 9
#define NB 10
#define ATTR 4

typedef __attribute__((ext_vector_type(8))) short bfrag8;  // 8 bf16 (4 VGPR)
typedef __attribute__((ext_vector_type(4))) float f32x4;
typedef unsigned int u32;
typedef unsigned short u16;

constexpr float INV_SQRT_NB = 0.17677669529663687f; // 1/sqrt(32)

__device__ __forceinline__ float silu_f(float x) { return x / (1.0f + __expf(-x)); }

__device__ __forceinline__ u16 f2bf(float v) {
    union { __hip_bfloat16 h; u16 u; } c;
    c.h = __float2bfloat16(v);
    return c.u;
}

__device__ __forceinline__ f32x4 mfma16(bfrag8 a, bfrag8 b, f32x4 c) {
    return __builtin_amdgcn_mfma_f32_16x16x32_bf16(a, b, c, 0, 0, 0);
}

// ---------------------------------------------------------------------------
// CSR build over dst; fill_k emits pos[e] = slot so msg can be written
// slot-ordered (gather becomes a sequential stream).
// ---------------------------------------------------------------------------
__global__ void count_k(const int* __restrict__ dst, int* __restrict__ cnt) {
    int i = blockIdx.x * blockDim.x + threadIdx.x;
    int st = gridDim.x * blockDim.x;
    for (; i < NE; i += st) atomicAdd(&cnt[dst[i]], 1);
}

__global__ void scan_k(const int* __restrict__ cnt, int* __restrict__ ptr) {
    __shared__ int ssum[256];
    const int T = 256, t = threadIdx.x;
    const int strip = (NN + T - 1) / T;
    int base = t * strip, s = 0;
    for (int i = 0; i < strip; i++) { int idx = base + i; if (idx < NN) s += cnt[idx]; }
    ssum[t] = s; __syncthreads();
    for (int off = 1; off < T; off <<= 1) {
        int v = (t >= off) ? ssum[t - off] : 0;
        __syncthreads();
        ssum[t] += v;
        __syncthreads();
    }
    int run = (t == 0) ? 0 : ssum[t - 1];
    for (int i = 0; i < strip; i++) {
        int idx = base + i;
        if (idx < NN) { int c = cnt[idx]; ptr[idx] = run; run += c; }
    }
    if (t == T - 1) ptr[NN] = run;
}

__global__ void fill_k(const int* __restrict__ dst, const int* __restrict__ ptr,
                       int* __restrict__ cnt, int* __restrict__ pos) {
    int i = blockIdx.x * blockDim.x + threadIdx.x;
    int st = gridDim.x * blockDim.x;
    for (; i < NE; i += st) {
        int d = dst[i];
        int r = atomicAdd(&cnt[d], 1);
        pos[i] = ptr[d] + r;
    }
}

// ---------------------------------------------------------------------------
// Pack a [K][N] f32 weight into MFMA B-fragment tiles (bf16, zero-padded):
// out[((t*KS+s)*64 + lane)*8 + j] = W[k = s*32+(lane>>4)*8+j][n = t*16+(lane&15)]
// ---------------------------------------------------------------------------
__global__ void pack_bfrag(const float* __restrict__ W, u16* __restrict__ out,
                           int K, int N, int NT, int KS) {
    int tid = blockIdx.x * blockDim.x + threadIdx.x;
    if (tid >= NT * KS * 64) return;
    int l = tid & 63, ts = tid >> 6, s = ts % KS, t = ts / KS;
    int kb = s * 32 + ((l >> 4) << 3);
    int n = t * 16 + (l & 15);
    #pragma unroll
    for (int j = 0; j < 8; j++) {
        int k = kb + j;
        float v = (k < K && n < N) ? W[(size_t)k * N + n] : 0.f;
        out[(size_t)tid * 8 + j] = f2bf(v);
    }
}

// ---------------------------------------------------------------------------
// Per-node prep: xa = x @ A   and   agg = outer(x, attr) @ Wsc  (self-conn)
// ---------------------------------------------------------------------------
template<int DI, int DO, int NT>
__global__ void node_prep(const float* __restrict__ xin,
                          const float* __restrict__ attr,
                          const float* __restrict__ A,
                          const float* __restrict__ Wsc,
                          float* __restrict__ xa,
                          float* __restrict__ agg)
{
    __shared__ float sx[NT][DI];
    __shared__ float sat[NT][ATTR];
    const int n0 = blockIdx.x * NT;
    for (int idx = threadIdx.x; idx < NT * DI; idx += blockDim.x)
        sx[idx / DI][idx % DI] = xin[(size_t)n0 * DI + idx];
    if (threadIdx.x < NT * ATTR)
        sat[threadIdx.x / ATTR][threadIdx.x % ATTR] = attr[(size_t)n0 * ATTR + threadIdx.x];
    __syncthreads();

    const int o = threadIdx.x;
    if (o < DO) {
        float at[NT][ATTR];
        #pragma unroll
        for (int n = 0; n < NT; n++) {
            at[n][0] = sat[n][0]; at[n][1] = sat[n][1];
            at[n][2] = sat[n][2]; at[n][3] = sat[n][3];
        }
        float accA[NT], accS[NT];
        #pragma unroll
        for (int n = 0; n < NT; n++) { accA[n] = 0.f; accS[n] = 0.f; }
        for (int i = 0; i < DI; i++) {
            float a  = A[(size_t)i * DO + o];
            float w0 = Wsc[(size_t)(i * 4 + 0) * DO + o];
            float w1 = Wsc[(size_t)(i * 4 + 1) * DO + o];
            float w2 = Wsc[(size_t)(i * 4 + 2) * DO + o];
            float w3 = Wsc[(size_t)(i * 4 + 3) * DO + o];
            #pragma unroll
            for (int n = 0; n < NT; n++) {
                float xi = sx[n][i];
                accA[n] = fmaf(xi, a, accA[n]);
                float s = fmaf(at[n][3], w3,
                          fmaf(at[n][2], w2,
                          fmaf(at[n][1], w1, at[n][0] * w0)));
                accS[n] = fmaf(xi, s, accS[n]);
            }
        }
        #pragma unroll
        for (int n = 0; n < NT; n++) {
            xa [(size_t)(n0 + n) * DO + o] = accA[n];
            agg[(size_t)(n0 + n) * DO + o] = accS[n];
        }
    }
}

// ---------------------------------------------------------------------------
// MFMA edge kernel. One wave = 16 edges/iter.
// Fragment layouts (gfx950 16x16x32 bf16):
//   A: row = lane&15, k = (lane>>4)*8 + j
//   B: col = lane&15, k = (lane>>4)*8 + j   (pre-packed by pack_bfrag)
//   C/D: col = lane&15, row = (lane>>4)*4 + reg  [m89-verified]
// h1/h2/msg LDS tiles are bf16 row-major with 32-dword-aligned rows and
// dword-index XOR swizzle  dw ^= (row&7)<<2  (bijective in-row, spreads banks).
// ---------------------------------------------------------------------------
template<int DO>
__global__ void __launch_bounds__(256, 2)
edge_mfma(const float* __restrict__ emb, const float* __restrict__ sh,
          const int* __restrict__ src, const int* __restrict__ pos,
          const u16* __restrict__ W1f, const u16* __restrict__ W2f,
          const u16* __restrict__ W3f, const u16* __restrict__ Bf,
          const float* __restrict__ xa, u32* __restrict__ msgdw,
          float* __restrict__ msg3)
{
    __shared__ u32 ldsa[4 * 2400];        // 9600 B per wave
    const int wid = threadIdx.x >> 6;
    const int l   = threadIdx.x & 63;
    u32* Wl = ldsa + wid * 2400;
    float* embL  = (float*)Wl;            // [16][10] f32  (dw   0..159)
    float* shL   = (float*)(Wl + 160);    // [16][9]  f32  (dw 160..303)
    int*   sidxL = (int*)(Wl + 304);      // [16]
    int*   posL  = (int*)(Wl + 320);      // [16]          (pad to 352)
    u32*   h1dw  = Wl + 352;              // [16][32] dw = bf16 [16][64]
    u32*   h2dw  = Wl + 864;              // [16][64] dw h2, reused as [16][96] dw msg

    const bfrag8* w1f = (const bfrag8*)W1f;
    const bfrag8* w2f = (const bfrag8*)W2f;
    const bfrag8* w3f = (const bfrag8*)W3f;
    const bfrag8* bff = (const bfrag8*)Bf;

    const int g = l >> 4, c = l & 15;
    const int gwave = blockIdx.x * 4 + wid;
    const int nwave = gridDim.x * 4;
    const f32x4 Z4 = {0.f, 0.f, 0.f, 0.f};

    for (int it = gwave; it < NE / 16; it += nwave) {
        const int e0 = it * 16;
        // ---- stage emb/sh/idx (per-wave LDS, no cross-wave sharing) ----
        {
            const float* ep = emb + (size_t)e0 * NB;
            for (int idx = l; idx < 16 * NB; idx += 64) embL[idx] = ep[idx];
            const float* sp = sh + (size_t)e0 * DSH;
            for (int idx = l; idx < 16 * DSH; idx += 64) shL[idx] = sp[idx];
            if (l < 16) { sidxL[l] = src[e0 + l]; posL[l] = pos[e0 + l]; }
        }
        // ---- A-frag of emb (K padded 10->32) ----
        bfrag8 a_emb;
        {
            const int kb = g << 3;
            #pragma unroll
            for (int j = 0; j < 8; j++) {
                int k = kb + j;
                float v = (k < NB) ? embL[c * NB + k] : 0.f;
                a_emb[j] = (short)f2bf(v);
            }
        }
        // ---- phase A: h1 = silu(emb @ W1), 4 MFMA -> LDS ----
        #pragma unroll
        for (int t = 0; t < 4; t++) {
            f32x4 acc = mfma16(a_emb, w1f[t * 64 + l], Z4);
            #pragma unroll
            for (int r = 0; r < 4; r++) {
                int m = g * 4 + r, n = t * 16 + c;
                int dw = (m * 32 + (n >> 1)) ^ ((m & 7) << 2);
                ((u16*)(h1dw + dw))[n & 1] = f2bf(silu_f(acc[r]));
            }
        }
        // ---- A-frags of h1 (2 k-steps) ----
        bfrag8 a_h1_0, a_h1_1;
        {
            int bb = c * 32 + g * 4, xr = (c & 7) << 2;
            a_h1_0 = *(const bfrag8*)(h1dw + ((bb +  0) ^ xr));
            a_h1_1 = *(const bfrag8*)(h1dw + ((bb + 16) ^ xr));
        }
        // ---- phase B: h2 = silu(h1 @ W2), 16 MFMA -> LDS ----
        #pragma unroll
        for (int t2 = 0; t2 < 8; t2++) {
            f32x4 acc = mfma16(a_h1_0, w2f[(t2 * 2 + 0) * 64 + l], Z4);
            acc = mfma16(a_h1_1, w2f[(t2 * 2 + 1) * 64 + l], acc);
            #pragma unroll
            for (int r = 0; r < 4; r++) {
                int m = g * 4 + r, n = t2 * 16 + c;
                int dw = (m * 64 + (n >> 1)) ^ ((m & 7) << 2);
                ((u16*)(h2dw + dw))[n & 1] = f2bf(silu_f(acc[r]));
            }
        }
        // ---- A-frags of h2 (4 k-steps); read BEFORE msg reuses the buffer ----
        bfrag8 a_h2_0, a_h2_1, a_h2_2, a_h2_3;
        {
            int bb = c * 64 + g * 4, xr = (c & 7) << 2;
            a_h2_0 = *(const bfrag8*)(h2dw + ((bb +  0) ^ xr));
            a_h2_1 = *(const bfrag8*)(h2dw + ((bb + 16) ^ xr));
            a_h2_2 = *(const bfrag8*)(h2dw + ((bb + 32) ^ xr));
            a_h2_3 = *(const bfrag8*)(h2dw + ((bb + 48) ^ xr));
        }
        // ---- A-frag of sh (K padded 9->32) ----
        bfrag8 a_sh;
        {
            const int kb = g << 3;
            #pragma unroll
            for (int j = 0; j < 8; j++) {
                int k = kb + j;
                float v = (k < DSH) ? shL[c * DSH + k] : 0.f;
                a_sh[j] = (short)f2bf(v);
            }
        }
        const int si0 = sidxL[g * 4 + 0], si1 = sidxL[g * 4 + 1];
        const int si2 = sidxL[g * 4 + 2], si3 = sidxL[g * 4 + 3];

        if constexpr (DO == 144) {
            // ---- phases C+D interleaved per 16-col tile (no reg arrays) ----
            #pragma unroll 1
            for (int t3 = 0; t3 < 9; t3++) {
                f32x4 shb = mfma16(a_sh, bff[t3 * 64 + l], Z4);
                f32x4 acc = mfma16(a_h2_0, w3f[(t3 * 4 + 0) * 64 + l], Z4);
                acc = mfma16(a_h2_1, w3f[(t3 * 4 + 1) * 64 + l], acc);
                acc = mfma16(a_h2_2, w3f[(t3 * 4 + 2) * 64 + l], acc);
                acc = mfma16(a_h2_3, w3f[(t3 * 4 + 3) * 64 + l], acc);
                const int n = t3 * 16 + c;
                float v0 = acc[0] * shb[0] * xa[(size_t)si0 * 144 + n] * INV_SQRT_NB;
                float v1 = acc[1] * shb[1] * xa[(size_t)si1 * 144 + n] * INV_SQRT_NB;
                float v2 = acc[2] * shb[2] * xa[(size_t)si2 * 144 + n] * INV_SQRT_NB;
                float v3 = acc[3] * shb[3] * xa[(size_t)si3 * 144 + n] * INV_SQRT_NB;
                int m0 = g * 4;
                int d0 = ((m0 + 0) * 96 + (n >> 1)) ^ (((m0 + 0) & 7) << 2);
                int d1 = ((m0 + 1) * 96 + (n >> 1)) ^ (((m0 + 1) & 7) << 2);
                int d2 = ((m0 + 2) * 96 + (n >> 1)) ^ (((m0 + 2) & 7) << 2);
                int d3 = ((m0 + 3) * 96 + (n >> 1)) ^ (((m0 + 3) & 7) << 2);
                ((u16*)(h2dw + d0))[n & 1] = f2bf(v0);
                ((u16*)(h2dw + d1))[n & 1] = f2bf(v1);
                ((u16*)(h2dw + d2))[n & 1] = f2bf(v2);
                ((u16*)(h2dw + d3))[n & 1] = f2bf(v3);
            }
            // ---- coalesced copy-out, slot-ordered rows ----
            for (int i = l; i < 1152; i += 64) {
                int m = i / 72;
                int xq = i - m * 72;
                u32 v = h2dw[(m * 96 + xq) ^ ((m & 7) << 2)];
                msgdw[(size_t)posL[m] * 72 + xq] = v;
            }
        } else {
            // ---- DO==3: single padded N-tile, direct f32 stores ----
            const int p0 = posL[g * 4 + 0], p1 = posL[g * 4 + 1];
            const int p2 = posL[g * 4 + 2], p3 = posL[g * 4 + 3];
            f32x4 shb = mfma16(a_sh, bff[l], Z4);
            f32x4 acc = mfma16(a_h2_0, w3f[0 * 64 + l], Z4);
            acc = mfma16(a_h2_1, w3f[1 * 64 + l], acc);
            acc = mfma16(a_h2_2, w3f[2 * 64 + l], acc);
            acc = mfma16(a_h2_3, w3f[3 * 64 + l], acc);
            if (c < 3) {
                msg3[(size_t)p0 * 3 + c] = acc[0] * shb[0] * xa[(size_t)si0 * 3 + c] * INV_SQRT_NB;
                msg3[(size_t)p1 * 3 + c] = acc[1] * shb[1] * xa[(size_t)si1 * 3 + c] * INV_SQRT_NB;
                msg3[(size_t)p2 * 3 + c] = acc[2] * shb[2] * xa[(size_t)si2 * 3 + c] * INV_SQRT_NB;
                msg3[(size_t)p3 * 3 + c] = acc[3] * shb[3] * xa[(size_t)si3 * 3 + c] * INV_SQRT_NB;
            }
        }
    }
}

// ---------------------------------------------------------------------------
// Streaming gather: msg is slot-ordered, so node n's messages are rows
// ptr[n]..ptr[n+1] — fully sequential reads. Wave per node.
// ---------------------------------------------------------------------------
template<int ACT>
__global__ void gather144(const u32* __restrict__ msgdw,
                          const int* __restrict__ ptr,
                          const float* __restrict__ sc,
                          float* __restrict__ outb)
{
    const int lane = threadIdx.x & 63;
    const int gw = blockIdx.x * (blockDim.x >> 6) + (threadIdx.x >> 6);
    const int nw = gridDim.x * (blockDim.x >> 6);
    for (int n = gw; n < NN; n += nw) {
        const int s0 = ptr[n], s1 = ptr[n + 1];
        float a0 = 0.f, a1 = 0.f, b0 = 0.f, b1 = 0.f;
        for (int s = s0; s < s1; s++) {
            u32 u = msgdw[(size_t)s * 72 + lane];
            a0 += __uint_as_float(u << 16);
            a1 += __uint_as_float(u & 0xffff0000u);
            if (lane < 8) {
                u32 v = msgdw[(size_t)s * 72 + 64 + lane];
                b0 += __uint_as_float(v << 16);
                b1 += __uint_as_float(v & 0xffff0000u);
            }
        }
        size_t base = (size_t)n * 144;
        float2 sv = *(const float2*)&sc[base + 2 * lane];
        float v0 = sv.x + a0, v1 = sv.y + a1;
        if (ACT) { v0 = silu_f(v0); v1 = silu_f(v1); }
        *(float2*)&outb[base + 2 * lane] = make_float2(v0, v1);
        if (lane < 8) {
            float2 sw = *(const float2*)&sc[base + 128 + 2 * lane];
            float w0 = sw.x + b0, w1 = sw.y + b1;
            if (ACT) { w0 = silu_f(w0); w1 = silu_f(w1); }
            *(float2*)&outb[base + 128 + 2 * lane] = make_float2(w0, w1);
        }
    }
}

__global__ void gather3(const float* __restrict__ msg3,
                        const int* __restrict__ ptr,
                        float* __restrict__ outb)
{
    int t = blockIdx.x * blockDim.x + threadIdx.x;
    if (t >= NN * 3) return;
    int n = t / 3, o = t - 3 * n;
    float a = 0.f;
    for (int s = ptr[n]; s < ptr[n + 1]; s++) a += msg3[(size_t)s * 3 + o];
    outb[t] += a;   // self-connection already written by node_prep
}

// ---------------------------------------------------------------------------
extern "C" void kernel_launch(void* const* d_in, const int* in_sizes, int n_in,
                              void* d_out, int out_size, void* d_ws, size_t ws_size,
                              hipStream_t stream) {
    const float* x    = (const float*)d_in[0];
    const float* attr = (const float*)d_in[1];
    const float* sh   = (const float*)d_in[2];
    const float* emb  = (const float*)d_in[3];
    const float* A0   = (const float*)d_in[4];
    const float* B0   = (const float*)d_in[5];
    const float* W1_0 = (const float*)d_in[6];
    const float* W2_0 = (const float*)d_in[7];
    const float* W3_0 = (const float*)d_in[8];
    const float* Wsc0 = (const float*)d_in[9];
    const float* A1   = (const float*)d_in[10];
    const float* B1   = (const float*)d_in[11];
    const float* W1_1 = (const float*)d_in[12];
    const float* W2_1 = (const float*)d_in[13];
    const float* W3_1 = (const float*)d_in[14];
    const float* Wsc1 = (const float*)d_in[15];
    const float* A2   = (const float*)d_in[16];
    const float* B2   = (const float*)d_in[17];
    const float* W1_2 = (const float*)d_in[18];
    const float* W2_2 = (const float*)d_in[19];
    const float* W3_2 = (const float*)d_in[20];
    const float* Wsc2 = (const float*)d_in[21];
    const int*   src  = (const int*)d_in[22];
    const int*   dst  = (const int*)d_in[23];
    float* out = (float*)d_out;

    // ---- carve workspace ----
    char* wp = (char*)d_ws;
    auto alloc = [&](size_t bytes) -> void* {
        void* r = (void*)wp;
        wp += (bytes + 255) & ~(size_t)255;
        return r;
    };
    float* xa   = (float*)alloc((size_t)NN * 144 * 4);
    float* agg  = (float*)alloc((size_t)NN * 144 * 4);
    float* hb0  = (float*)alloc((size_t)NN * 144 * 4);
    float* hb1  = (float*)alloc((size_t)NN * 144 * 4);
    int*   cnt  = (int*)alloc((size_t)NN * 4);
    int*   ptr  = (int*)alloc((size_t)(NN + 1) * 4);
    int*   pos  = (int*)alloc((size_t)NE * 4);
    u16* w1f0 = (u16*)alloc(4 * 64 * 8 * 2);
    u16* w2f0 = (u16*)alloc(16 * 64 * 8 * 2);
    u16* w3f0 = (u16*)alloc(36 * 64 * 8 * 2);
    u16* bf0  = (u16*)alloc(9 * 64 * 8 * 2);
    u16* w1f1 = (u16*)alloc(4 * 64 * 8 * 2);
    u16* w2f1 = (u16*)alloc(16 * 64 * 8 * 2);
    u16* w3f1 = (u16*)alloc(36 * 64 * 8 * 2);
    u16* bf1  = (u16*)alloc(9 * 64 * 8 * 2);
    u16* w1f2 = (u16*)alloc(4 * 64 * 8 * 2);
    u16* w2f2 = (u16*)alloc(16 * 64 * 8 * 2);
    u16* w3f2 = (u16*)alloc(4 * 64 * 8 * 2);
    u16* bf2  = (u16*)alloc(1 * 64 * 8 * 2);
    void* msgbuf = alloc((size_t)NE * 288);      // bf16 [E][144] == u32 [E][72]
    u32*   msgdw = (u32*)msgbuf;
    float* msg3  = (float*)msgbuf;               // layer-2 f32 [E][3] aliases

    // ---- CSR build (dst identical across layers) ----
    hipMemsetAsync(cnt, 0, (size_t)NN * 4, stream);
    count_k<<<1024, 256, 0, stream>>>(dst, cnt);
    scan_k<<<1, 256, 0, stream>>>(cnt, ptr);
    hipMemsetAsync(cnt, 0, (size_t)NN * 4, stream);
    fill_k<<<1024, 256, 0, stream>>>(dst, ptr, cnt, pos);

    // ---- weight fragment packing ----
    pack_bfrag<<<1, 256, 0, stream>>>(W1_0, w1f0, 10, 64, 4, 1);
    pack_bfrag<<<4, 256, 0, stream>>>(W2_0, w2f0, 64, 128, 8, 2);
    pack_bfrag<<<9, 256, 0, stream>>>(W3_0, w3f0, 128, 144, 9, 4);
    pack_bfrag<<<3, 256, 0, stream>>>(B0,   bf0,  9, 144, 9, 1);
    pack_bfrag<<<1, 256, 0, stream>>>(W1_1, w1f1, 10, 64, 4, 1);
    pack_bfrag<<<4, 256, 0, stream>>>(W2_1, w2f1, 64, 128, 8, 2);
    pack_bfrag<<<9, 256, 0, stream>>>(W3_1, w3f1, 128, 144, 9, 4);
    pack_bfrag<<<3, 256, 0, stream>>>(B1,   bf1,  9, 144, 9, 1);
    pack_bfrag<<<1, 256, 0, stream>>>(W1_2, w1f2, 10, 64, 4, 1);
    pack_bfrag<<<4, 256, 0, stream>>>(W2_2, w2f2, 64, 128, 8, 2);
    pack_bfrag<<<1, 256, 0, stream>>>(W3_2, w3f2, 128, 3, 1, 4);
    pack_bfrag<<<1, 256, 0, stream>>>(B2,   bf2,  9, 3, 1, 1);

    // ---- layer 0 (di=64, do=144) ----
    node_prep<64, 144, 8><<<NN / 8, 192, 0, stream>>>(x, attr, A0, Wsc0, xa, agg);
    edge_mfma<144><<<1024, 256, 0, stream>>>(emb, sh, src, pos, w1f0, w2f0, w3f0, bf0, xa, msgdw, nullptr);
    gather144<1><<<5000, 256, 0, stream>>>(msgdw, ptr, agg, hb0);

    // ---- layer 1 (di=144, do=144) ----
    node_prep<144, 144, 8><<<NN / 8, 192, 0, stream>>>(hb0, attr, A1, Wsc1, xa, agg);
    edge_mfma<144><<<1024, 256, 0, stream>>>(emb, sh, src, pos, w1f1, w2f1, w3f1, bf1, xa, msgdw, nullptr);
    gather144<1><<<5000, 256, 0, stream>>>(msgdw, ptr, agg, hb1);

    // ---- layer 2 (di=144, do=3) ----
    node_prep<144, 3, 8><<<NN / 8, 192, 0, stream>>>(hb1, attr, A2, Wsc2, xa, out);
    edge_mfma<3><<<1024, 256, 0, stream>>>(emb, sh, src, pos, w1f2, w2f2, w3f2, bf2, xa, nullptr, msg3);
    gather3<<<(NN * 3 + 255) / 256, 256, 0, stream>>>(msg3, ptr, out);
}

// Round 7
// 1315.394 us; speedup vs baseline: 4.8871x; 1.1722x over previous
//
#include <hip/hip_runtime.h>
#include <hip/hip_bf16.h>

#define NN 20000
#define NE 640000
#define DSH 9
#define NB 10
#define ATTR 4

typedef __attribute__((ext_vector_type(8))) short bfrag8;  // 8 bf16 (4 VGPR)
typedef __attribute__((ext_vector_type(4))) float f32x4;
typedef unsigned int u32;
typedef unsigned short u16;

constexpr float INV_SQRT_NB = 0.17677669529663687f; // 1/sqrt(32)

__device__ __forceinline__ float silu_f(float x) { return x / (1.0f + __expf(-x)); }

__device__ __forceinline__ u16 f2bf(float v) {
    union { __hip_bfloat16 h; u16 u; } c;
    c.h = __float2bfloat16(v);
    return c.u;
}

__device__ __forceinline__ f32x4 mfma16(bfrag8 a, bfrag8 b, f32x4 c) {
    return __builtin_amdgcn_mfma_f32_16x16x32_bf16(a, b, c, 0, 0, 0);
}

// ---------------------------------------------------------------------------
// CSR build over dst; fill_k emits pos[e] = slot so msg can be written
// slot-ordered (gather becomes a sequential stream).  [R4-exact]
// ---------------------------------------------------------------------------
__global__ void count_k(const int* __restrict__ dst, int* __restrict__ cnt) {
    int i = blockIdx.x * blockDim.x + threadIdx.x;
    int st = gridDim.x * blockDim.x;
    for (; i < NE; i += st) atomicAdd(&cnt[dst[i]], 1);
}

__global__ void scan_k(const int* __restrict__ cnt, int* __restrict__ ptr) {
    __shared__ int ssum[256];
    const int T = 256, t = threadIdx.x;
    const int strip = (NN + T - 1) / T;
    int base = t * strip, s = 0;
    for (int i = 0; i < strip; i++) { int idx = base + i; if (idx < NN) s += cnt[idx]; }
    ssum[t] = s; __syncthreads();
    for (int off = 1; off < T; off <<= 1) {
        int v = (t >= off) ? ssum[t - off] : 0;
        __syncthreads();
        ssum[t] += v;
        __syncthreads();
    }
    int run = (t == 0) ? 0 : ssum[t - 1];
    for (int i = 0; i < strip; i++) {
        int idx = base + i;
        if (idx < NN) { int c = cnt[idx]; ptr[idx] = run; run += c; }
    }
    if (t == T - 1) ptr[NN] = run;
}

__global__ void fill_k(const int* __restrict__ dst, const int* __restrict__ ptr,
                       int* __restrict__ cnt, int* __restrict__ pos) {
    int i = blockIdx.x * blockDim.x + threadIdx.x;
    int st = gridDim.x * blockDim.x;
    for (; i < NE; i += st) {
        int d = dst[i];
        int r = atomicAdd(&cnt[d], 1);
        pos[i] = ptr[d] + r;
    }
}

// ---------------------------------------------------------------------------
// Pack a [K][N] f32 weight into MFMA B-fragment tiles (bf16, zero-padded)
// [R4-exact]
// ---------------------------------------------------------------------------
__global__ void pack_bfrag(const float* __restrict__ W, u16* __restrict__ out,
                           int K, int N, int NT, int KS) {
    int tid = blockIdx.x * blockDim.x + threadIdx.x;
    if (tid >= NT * KS * 64) return;
    int l = tid & 63, ts = tid >> 6, s = ts % KS, t = ts / KS;
    int kb = s * 32 + ((l >> 4) << 3);
    int n = t * 16 + (l & 15);
    #pragma unroll
    for (int j = 0; j < 8; j++) {
        int k = kb + j;
        float v = (k < K && n < N) ? W[(size_t)k * N + n] : 0.f;
        out[(size_t)tid * 8 + j] = f2bf(v);
    }
}

// ---------------------------------------------------------------------------
// Per-node prep: xa = x @ A   and   agg = outer(x, attr) @ Wsc  [R4-exact]
// ---------------------------------------------------------------------------
template<int DI, int DO, int NT>
__global__ void node_prep(const float* __restrict__ xin,
                          const float* __restrict__ attr,
                          const float* __restrict__ A,
                          const float* __restrict__ Wsc,
                          float* __restrict__ xa,
                          float* __restrict__ agg)
{
    __shared__ float sx[NT][DI];
    __shared__ float sat[NT][ATTR];
    const int n0 = blockIdx.x * NT;
    for (int idx = threadIdx.x; idx < NT * DI; idx += blockDim.x)
        sx[idx / DI][idx % DI] = xin[(size_t)n0 * DI + idx];
    if (threadIdx.x < NT * ATTR)
        sat[threadIdx.x / ATTR][threadIdx.x % ATTR] = attr[(size_t)n0 * ATTR + threadIdx.x];
    __syncthreads();

    const int o = threadIdx.x;
    if (o < DO) {
        float at[NT][ATTR];
        #pragma unroll
        for (int n = 0; n < NT; n++) {
            at[n][0] = sat[n][0]; at[n][1] = sat[n][1];
            at[n][2] = sat[n][2]; at[n][3] = sat[n][3];
        }
        float accA[NT], accS[NT];
        #pragma unroll
        for (int n = 0; n < NT; n++) { accA[n] = 0.f; accS[n] = 0.f; }
        for (int i = 0; i < DI; i++) {
            float a  = A[(size_t)i * DO + o];
            float w0 = Wsc[(size_t)(i * 4 + 0) * DO + o];
            float w1 = Wsc[(size_t)(i * 4 + 1) * DO + o];
            float w2 = Wsc[(size_t)(i * 4 + 2) * DO + o];
            float w3 = Wsc[(size_t)(i * 4 + 3) * DO + o];
            #pragma unroll
            for (int n = 0; n < NT; n++) {
                float xi = sx[n][i];
                accA[n] = fmaf(xi, a, accA[n]);
                float s = fmaf(at[n][3], w3,
                          fmaf(at[n][2], w2,
                          fmaf(at[n][1], w1, at[n][0] * w0)));
                accS[n] = fmaf(xi, s, accS[n]);
            }
        }
        #pragma unroll
        for (int n = 0; n < NT; n++) {
            xa [(size_t)(n0 + n) * DO + o] = accA[n];
            agg[(size_t)(n0 + n) * DO + o] = accS[n];
        }
    }
}

// ---------------------------------------------------------------------------
// MFMA edge kernel. R4-exact EXCEPT:
//  (a) all 36 xa-gather loads hoisted to right after staging (their miss
//      latency overlaps phases A+B instead of serializing inside t3)
//  (b) t3 loop fully unrolled so xv[] is static-indexed (registers)
//  (c) no min-waves clause: VGPR floats (~200) instead of spilling at 128
// Staging is R4's direct global->LDS (the R6 register-prefetch is REVERTED).
// Fragment layouts (gfx950 16x16x32 bf16):
//   A: row=lane&15, k=(lane>>4)*8+j ; C/D: col=lane&15, row=(lane>>4)*4+reg
// ---------------------------------------------------------------------------
template<int DO>
__global__ void __launch_bounds__(256)
edge_mfma(const float* __restrict__ emb, const float* __restrict__ sh,
          const int* __restrict__ src, const int* __restrict__ pos,
          const u16* __restrict__ W1f, const u16* __restrict__ W2f,
          const u16* __restrict__ W3f, const u16* __restrict__ Bf,
          const float* __restrict__ xa, u32* __restrict__ msgdw,
          float* __restrict__ msg3)
{
    __shared__ u32 ldsa[4 * 2400];        // 9600 B per wave
    const int wid = threadIdx.x >> 6;
    const int l   = threadIdx.x & 63;
    u32* Wl = ldsa + wid * 2400;
    float* embL  = (float*)Wl;            // [16][10] f32  (dw   0..159)
    float* shL   = (float*)(Wl + 160);    // [16][9]  f32  (dw 160..303)
    int*   sidxL = (int*)(Wl + 304);      // [16]
    int*   posL  = (int*)(Wl + 320);      // [16]          (pad to 352)
    u32*   h1dw  = Wl + 352;              // [16][32] dw = bf16 [16][64]
    u32*   h2dw  = Wl + 864;              // [16][64] dw h2, reused as [16][96] dw msg

    const bfrag8* w1f = (const bfrag8*)W1f;
    const bfrag8* w2f = (const bfrag8*)W2f;
    const bfrag8* w3f = (const bfrag8*)W3f;
    const bfrag8* bff = (const bfrag8*)Bf;

    const int g = l >> 4, c = l & 15;
    const int gwave = blockIdx.x * 4 + wid;
    const int nwave = gridDim.x * 4;
    const f32x4 Z4 = {0.f, 0.f, 0.f, 0.f};

    for (int it = gwave; it < NE / 16; it += nwave) {
        const int e0 = it * 16;
        // ---- stage emb/sh/idx (R4-exact direct global->LDS) ----
        {
            const float* ep = emb + (size_t)e0 * NB;
            for (int idx = l; idx < 16 * NB; idx += 64) embL[idx] = ep[idx];
            const float* sp = sh + (size_t)e0 * DSH;
            for (int idx = l; idx < 16 * DSH; idx += 64) shL[idx] = sp[idx];
            if (l < 16) { sidxL[l] = src[e0 + l]; posL[l] = pos[e0 + l]; }
        }
        // ---- read src indices; issue ALL xa-gather loads up front ----
        const int si0 = sidxL[g * 4 + 0], si1 = sidxL[g * 4 + 1];
        const int si2 = sidxL[g * 4 + 2], si3 = sidxL[g * 4 + 3];
        float xv[(DO == 144) ? 36 : 1];
        if constexpr (DO == 144) {
            const float* xr0 = xa + (size_t)si0 * 144;
            const float* xr1 = xa + (size_t)si1 * 144;
            const float* xr2 = xa + (size_t)si2 * 144;
            const float* xr3 = xa + (size_t)si3 * 144;
            #pragma unroll
            for (int t3 = 0; t3 < 9; t3++) {
                xv[t3 * 4 + 0] = xr0[t3 * 16 + c];
                xv[t3 * 4 + 1] = xr1[t3 * 16 + c];
                xv[t3 * 4 + 2] = xr2[t3 * 16 + c];
                xv[t3 * 4 + 3] = xr3[t3 * 16 + c];
            }
        }
        // ---- A-frag of emb (K padded 10->32) ----
        bfrag8 a_emb;
        {
            const int kb = g << 3;
            #pragma unroll
            for (int j = 0; j < 8; j++) {
                int k = kb + j;
                float v = (k < NB) ? embL[c * NB + k] : 0.f;
                a_emb[j] = (short)f2bf(v);
            }
        }
        // ---- phase A: h1 = silu(emb @ W1), 4 MFMA -> LDS ----
        #pragma unroll
        for (int t = 0; t < 4; t++) {
            f32x4 acc = mfma16(a_emb, w1f[t * 64 + l], Z4);
            #pragma unroll
            for (int r = 0; r < 4; r++) {
                int m = g * 4 + r, n = t * 16 + c;
                int dw = (m * 32 + (n >> 1)) ^ ((m & 7) << 2);
                ((u16*)(h1dw + dw))[n & 1] = f2bf(silu_f(acc[r]));
            }
        }
        bfrag8 a_h1_0, a_h1_1;
        {
            int bb = c * 32 + g * 4, xr = (c & 7) << 2;
            a_h1_0 = *(const bfrag8*)(h1dw + ((bb +  0) ^ xr));
            a_h1_1 = *(const bfrag8*)(h1dw + ((bb + 16) ^ xr));
        }
        // ---- phase B: h2 = silu(h1 @ W2), 16 MFMA -> LDS ----
        #pragma unroll
        for (int t2 = 0; t2 < 8; t2++) {
            f32x4 acc = mfma16(a_h1_0, w2f[(t2 * 2 + 0) * 64 + l], Z4);
            acc = mfma16(a_h1_1, w2f[(t2 * 2 + 1) * 64 + l], acc);
            #pragma unroll
            for (int r = 0; r < 4; r++) {
                int m = g * 4 + r, n = t2 * 16 + c;
                int dw = (m * 64 + (n >> 1)) ^ ((m & 7) << 2);
                ((u16*)(h2dw + dw))[n & 1] = f2bf(silu_f(acc[r]));
            }
        }
        bfrag8 a_h2_0, a_h2_1, a_h2_2, a_h2_3;
        {
            int bb = c * 64 + g * 4, xr = (c & 7) << 2;
            a_h2_0 = *(const bfrag8*)(h2dw + ((bb +  0) ^ xr));
            a_h2_1 = *(const bfrag8*)(h2dw + ((bb + 16) ^ xr));
            a_h2_2 = *(const bfrag8*)(h2dw + ((bb + 32) ^ xr));
            a_h2_3 = *(const bfrag8*)(h2dw + ((bb + 48) ^ xr));
        }
        // ---- A-frag of sh (K padded 9->32) ----
        bfrag8 a_sh;
        {
            const int kb = g << 3;
            #pragma unroll
            for (int j = 0; j < 8; j++) {
                int k = kb + j;
                float v = (k < DSH) ? shL[c * DSH + k] : 0.f;
                a_sh[j] = (short)f2bf(v);
            }
        }
        const int si0u = si0, si1u = si1, si2u = si2, si3u = si3;

        if constexpr (DO == 144) {
            // ---- phases C+D per 16-col tile, xa already in registers ----
            #pragma unroll
            for (int t3 = 0; t3 < 9; t3++) {
                f32x4 shb = mfma16(a_sh, bff[t3 * 64 + l], Z4);
                f32x4 acc = mfma16(a_h2_0, w3f[(t3 * 4 + 0) * 64 + l], Z4);
                acc = mfma16(a_h2_1, w3f[(t3 * 4 + 1) * 64 + l], acc);
                acc = mfma16(a_h2_2, w3f[(t3 * 4 + 2) * 64 + l], acc);
                acc = mfma16(a_h2_3, w3f[(t3 * 4 + 3) * 64 + l], acc);
                const int n = t3 * 16 + c;
                float v0 = acc[0] * shb[0] * xv[t3 * 4 + 0] * INV_SQRT_NB;
                float v1 = acc[1] * shb[1] * xv[t3 * 4 + 1] * INV_SQRT_NB;
                float v2 = acc[2] * shb[2] * xv[t3 * 4 + 2] * INV_SQRT_NB;
                float v3 = acc[3] * shb[3] * xv[t3 * 4 + 3] * INV_SQRT_NB;
                int m0 = g * 4;
                int d0 = ((m0 + 0) * 96 + (n >> 1)) ^ (((m0 + 0) & 7) << 2);
                int d1 = ((m0 + 1) * 96 + (n >> 1)) ^ (((m0 + 1) & 7) << 2);
                int d2 = ((m0 + 2) * 96 + (n >> 1)) ^ (((m0 + 2) & 7) << 2);
                int d3 = ((m0 + 3) * 96 + (n >> 1)) ^ (((m0 + 3) & 7) << 2);
                ((u16*)(h2dw + d0))[n & 1] = f2bf(v0);
                ((u16*)(h2dw + d1))[n & 1] = f2bf(v1);
                ((u16*)(h2dw + d2))[n & 1] = f2bf(v2);
                ((u16*)(h2dw + d3))[n & 1] = f2bf(v3);
            }
            // ---- coalesced copy-out, slot-ordered rows ----
            for (int i = l; i < 1152; i += 64) {
                int m = i / 72;
                int xq = i - m * 72;
                u32 v = h2dw[(m * 96 + xq) ^ ((m & 7) << 2)];
                msgdw[(size_t)posL[m] * 72 + xq] = v;
            }
        } else {
            // ---- DO==3: single padded N-tile, direct f32 stores [R4-exact] ----
            const int p0 = posL[g * 4 + 0], p1 = posL[g * 4 + 1];
            const int p2 = posL[g * 4 + 2], p3 = posL[g * 4 + 3];
            f32x4 shb = mfma16(a_sh, bff[l], Z4);
            f32x4 acc = mfma16(a_h2_0, w3f[0 * 64 + l], Z4);
            acc = mfma16(a_h2_1, w3f[1 * 64 + l], acc);
            acc = mfma16(a_h2_2, w3f[2 * 64 + l], acc);
            acc = mfma16(a_h2_3, w3f[3 * 64 + l], acc);
            if (c < 3) {
                msg3[(size_t)p0 * 3 + c] = acc[0] * shb[0] * xa[(size_t)si0u * 3 + c] * INV_SQRT_NB;
                msg3[(size_t)p1 * 3 + c] = acc[1] * shb[1] * xa[(size_t)si1u * 3 + c] * INV_SQRT_NB;
                msg3[(size_t)p2 * 3 + c] = acc[2] * shb[2] * xa[(size_t)si2u * 3 + c] * INV_SQRT_NB;
                msg3[(size_t)p3 * 3 + c] = acc[3] * shb[3] * xa[(size_t)si3u * 3 + c] * INV_SQRT_NB;
            }
        }
    }
}

// ---------------------------------------------------------------------------
// Streaming gather: msg is slot-ordered; node n's messages are rows
// ptr[n]..ptr[n+1] — fully sequential reads. Wave per node.  [R4-exact]
// ---------------------------------------------------------------------------
template<int ACT>
__global__ void gather144(const u32* __restrict__ msgdw,
                          const int* __restrict__ ptr,
                          const float* __restrict__ sc,
                          float* __restrict__ outb)
{
    const int lane = threadIdx.x & 63;
    const int gw = blockIdx.x * (blockDim.x >> 6) + (threadIdx.x >> 6);
    const int nw = gridDim.x * (blockDim.x >> 6);
    for (int n = gw; n < NN; n += nw) {
        const int s0 = ptr[n], s1 = ptr[n + 1];
        float a0 = 0.f, a1 = 0.f, b0 = 0.f, b1 = 0.f;
        for (int s = s0; s < s1; s++) {
            u32 u = msgdw[(size_t)s * 72 + lane];
            a0 += __uint_as_float(u << 16);
            a1 += __uint_as_float(u & 0xffff0000u);
            if (lane < 8) {
                u32 v = msgdw[(size_t)s * 72 + 64 + lane];
                b0 += __uint_as_float(v << 16);
                b1 += __uint_as_float(v & 0xffff0000u);
            }
        }
        size_t base = (size_t)n * 144;
        float2 sv = *(const float2*)&sc[base + 2 * lane];
        float v0 = sv.x + a0, v1 = sv.y + a1;
        if (ACT) { v0 = silu_f(v0); v1 = silu_f(v1); }
        *(float2*)&outb[base + 2 * lane] = make_float2(v0, v1);
        if (lane < 8) {
            float2 sw = *(const float2*)&sc[base + 128 + 2 * lane];
            float w0 = sw.x + b0, w1 = sw.y + b1;
            if (ACT) { w0 = silu_f(w0); w1 = silu_f(w1); }
            *(float2*)&outb[base + 128 + 2 * lane] = make_float2(w0, w1);
        }
    }
}

__global__ void gather3(const float* __restrict__ msg3,
                        const int* __restrict__ ptr,
                        float* __restrict__ outb)
{
    int t = blockIdx.x * blockDim.x + threadIdx.x;
    if (t >= NN * 3) return;
    int n = t / 3, o = t - 3 * n;
    float a = 0.f;
    for (int s = ptr[n]; s < ptr[n + 1]; s++) a += msg3[(size_t)s * 3 + o];
    outb[t] += a;   // self-connection already written by node_prep
}

// ---------------------------------------------------------------------------
extern "C" void kernel_launch(void* const* d_in, const int* in_sizes, int n_in,
                              void* d_out, int out_size, void* d_ws, size_t ws_size,
                              hipStream_t stream) {
    const float* x    = (const float*)d_in[0];
    const float* attr = (const float*)d_in[1];
    const float* sh   = (const float*)d_in[2];
    const float* emb  = (const float*)d_in[3];
    const float* A0   = (const float*)d_in[4];
    const float* B0   = (const float*)d_in[5];
    const float* W1_0 = (const float*)d_in[6];
    const float* W2_0 = (const float*)d_in[7];
    const float* W3_0 = (const float*)d_in[8];
    const float* Wsc0 = (const float*)d_in[9];
    const float* A1   = (const float*)d_in[10];
    const float* B1   = (const float*)d_in[11];
    const float* W1_1 = (const float*)d_in[12];
    const float* W2_1 = (const float*)d_in[13];
    const float* W3_1 = (const float*)d_in[14];
    const float* Wsc1 = (const float*)d_in[15];
    const float* A2   = (const float*)d_in[16];
    const float* B2   = (const float*)d_in[17];
    const float* W1_2 = (const float*)d_in[18];
    const float* W2_2 = (const float*)d_in[19];
    const float* W3_2 = (const float*)d_in[20];
    const float* Wsc2 = (const float*)d_in[21];
    const int*   src  = (const int*)d_in[22];
    const int*   dst  = (const int*)d_in[23];
    float* out = (float*)d_out;

    // ---- carve workspace (R4-exact) ----
    char* wp = (char*)d_ws;
    auto alloc = [&](size_t bytes) -> void* {
        void* r = (void*)wp;
        wp += (bytes + 255) & ~(size_t)255;
        return r;
    };
    float* xa   = (float*)alloc((size_t)NN * 144 * 4);
    float* agg  = (float*)alloc((size_t)NN * 144 * 4);
    float* hb0  = (float*)alloc((size_t)NN * 144 * 4);
    float* hb1  = (float*)alloc((size_t)NN * 144 * 4);
    int*   cnt  = (int*)alloc((size_t)NN * 4);
    int*   ptr  = (int*)alloc((size_t)(NN + 1) * 4);
    int*   pos  = (int*)alloc((size_t)NE * 4);
    u16* w1f0 = (u16*)alloc(4 * 64 * 8 * 2);
    u16* w2f0 = (u16*)alloc(16 * 64 * 8 * 2);
    u16* w3f0 = (u16*)alloc(36 * 64 * 8 * 2);
    u16* bf0  = (u16*)alloc(9 * 64 * 8 * 2);
    u16* w1f1 = (u16*)alloc(4 * 64 * 8 * 2);
    u16* w2f1 = (u16*)alloc(16 * 64 * 8 * 2);
    u16* w3f1 = (u16*)alloc(36 * 64 * 8 * 2);
    u16* bf1  = (u16*)alloc(9 * 64 * 8 * 2);
    u16* w1f2 = (u16*)alloc(4 * 64 * 8 * 2);
    u16* w2f2 = (u16*)alloc(16 * 64 * 8 * 2);
    u16* w3f2 = (u16*)alloc(4 * 64 * 8 * 2);
    u16* bf2  = (u16*)alloc(1 * 64 * 8 * 2);
    void* msgbuf = alloc((size_t)NE * 288);      // bf16 [E][144] == u32 [E][72]
    u32*   msgdw = (u32*)msgbuf;
    float* msg3  = (float*)msgbuf;               // layer-2 f32 [E][3] aliases

    // ---- CSR build (dst identical across layers) ----
    hipMemsetAsync(cnt, 0, (size_t)NN * 4, stream);
    count_k<<<1024, 256, 0, stream>>>(dst, cnt);
    scan_k<<<1, 256, 0, stream>>>(cnt, ptr);
    hipMemsetAsync(cnt, 0, (size_t)NN * 4, stream);
    fill_k<<<1024, 256, 0, stream>>>(dst, ptr, cnt, pos);

    // ---- weight fragment packing ----
    pack_bfrag<<<1, 256, 0, stream>>>(W1_0, w1f0, 10, 64, 4, 1);
    pack_bfrag<<<4, 256, 0, stream>>>(W2_0, w2f0, 64, 128, 8, 2);
    pack_bfrag<<<9, 256, 0, stream>>>(W3_0, w3f0, 128, 144, 9, 4);
    pack_bfrag<<<3, 256, 0, stream>>>(B0,   bf0,  9, 144, 9, 1);
    pack_bfrag<<<1, 256, 0, stream>>>(W1_1, w1f1, 10, 64, 4, 1);
    pack_bfrag<<<4, 256, 0, stream>>>(W2_1, w2f1, 64, 128, 8, 2);
    pack_bfrag<<<9, 256, 0, stream>>>(W3_1, w3f1, 128, 144, 9, 4);
    pack_bfrag<<<3, 256, 0, stream>>>(B1,   bf1,  9, 144, 9, 1);
    pack_bfrag<<<1, 256, 0, stream>>>(W1_2, w1f2, 10, 64, 4, 1);
    pack_bfrag<<<4, 256, 0, stream>>>(W2_2, w2f2, 64, 128, 8, 2);
    pack_bfrag<<<1, 256, 0, stream>>>(W3_2, w3f2, 128, 3, 1, 4);
    pack_bfrag<<<1, 256, 0, stream>>>(B2,   bf2,  9, 3, 1, 1);

    // ---- layer 0 (di=64, do=144) ----
    node_prep<64, 144, 8><<<NN / 8, 192, 0, stream>>>(x, attr, A0, Wsc0, xa, agg);
    edge_mfma<144><<<2500, 256, 0, stream>>>(emb, sh, src, pos, w1f0, w2f0, w3f0, bf0, xa, msgdw, nullptr);
    gather144<1><<<5000, 256, 0, stream>>>(msgdw, ptr, agg, hb0);

    // ---- layer 1 (di=144, do=144) ----
    node_prep<144, 144, 8><<<NN / 8, 192, 0, stream>>>(hb0, attr, A1, Wsc1, xa, agg);
    edge_mfma<144><<<2500, 256, 0, stream>>>(emb, sh, src, pos, w1f1, w2f1, w3f1, bf1, xa, msgdw, nullptr);
    gather144<1><<<5000, 256, 0, stream>>>(msgdw, ptr, agg, hb1);

    // ---- layer 2 (di=144, do=3) ----
    node_prep<144, 3, 8><<<NN / 8, 192, 0, stream>>>(hb1, attr, A2, Wsc2, xa, out);
    edge_mfma<3><<<2500, 256, 0, stream>>>(emb, sh, src, pos, w1f2, w2f2, w3f2, bf2, xa, nullptr, msg3);
    gather3<<<(NN * 3 + 255) / 256, 256, 0, stream>>>(msg3, ptr, out);
}